// Round 1
// baseline (1503.784 us; speedup 1.0000x reference)
//
#include <hip/hip_runtime.h>
#include <math.h>

#define D_MODEL 1024
#define D_INNER 2048
#define D_STATE 16
#define DT_RANK 64
#define LSEQ 2048
#define NBATCH 2
#define M_TOT (NBATCH * LSEQ)   // 4096 rows total

// ---------------------------------------------------------------------------
// fp32 tiled GEMM: C[M,N] = A[M,K] @ B[K,N], all row-major, dims divisible by
// tile. 128x128 block tile, 8x8 per-thread microtile, BK=16, 256 threads.
// ---------------------------------------------------------------------------
template <int BM, int BN, int BK>
__global__ __launch_bounds__(256) void gemm_f32(
    const float* __restrict__ A, const float* __restrict__ B,
    float* __restrict__ C, int M, int N, int K)
{
    __shared__ float As[BK][BM + 4];   // +4 pad keeps 16B alignment, breaks conflicts
    __shared__ float Bs[BK][BN];
    const int tid = threadIdx.x;
    const int m0 = blockIdx.y * BM, n0 = blockIdx.x * BN;
    const int tx = tid & 15, ty = tid >> 4;   // 16x16 thread grid
    float acc[8][8] = {};

    for (int k0 = 0; k0 < K; k0 += BK) {
        // A tile: BM x BK = 2048 floats = 512 float4, 2 per thread (transpose into As)
        #pragma unroll
        for (int j = 0; j < (BM * BK) / (256 * 4); ++j) {
            int i = tid + 256 * j;
            int r = i >> 2, c4 = (i & 3) << 2;   // BK=16 -> 4 float4 per row
            float4 v = *reinterpret_cast<const float4*>(A + (size_t)(m0 + r) * K + k0 + c4);
            As[c4 + 0][r] = v.x; As[c4 + 1][r] = v.y;
            As[c4 + 2][r] = v.z; As[c4 + 3][r] = v.w;
        }
        // B tile: BK x BN = 2048 floats, 2 float4 per thread
        #pragma unroll
        for (int j = 0; j < (BK * BN) / (256 * 4); ++j) {
            int i = tid + 256 * j;
            int r = i / (BN / 4), c4 = (i % (BN / 4)) << 2;
            float4 v = *reinterpret_cast<const float4*>(B + (size_t)(k0 + r) * N + n0 + c4);
            *reinterpret_cast<float4*>(&Bs[r][c4]) = v;
        }
        __syncthreads();
        #pragma unroll
        for (int k = 0; k < BK; ++k) {
            float a[8], b[8];
            *reinterpret_cast<float4*>(&a[0]) = *reinterpret_cast<const float4*>(&As[k][ty * 8]);
            *reinterpret_cast<float4*>(&a[4]) = *reinterpret_cast<const float4*>(&As[k][ty * 8 + 4]);
            *reinterpret_cast<float4*>(&b[0]) = *reinterpret_cast<const float4*>(&Bs[k][tx * 8]);
            *reinterpret_cast<float4*>(&b[4]) = *reinterpret_cast<const float4*>(&Bs[k][tx * 8 + 4]);
            #pragma unroll
            for (int i = 0; i < 8; ++i)
                #pragma unroll
                for (int j = 0; j < 8; ++j)
                    acc[i][j] += a[i] * b[j];
        }
        __syncthreads();
    }
    #pragma unroll
    for (int i = 0; i < 8; ++i) {
        size_t row = (size_t)(m0 + ty * 8 + i) * N + n0 + tx * 8;
        *reinterpret_cast<float4*>(C + row)     = make_float4(acc[i][0], acc[i][1], acc[i][2], acc[i][3]);
        *reinterpret_cast<float4*>(C + row + 4) = make_float4(acc[i][4], acc[i][5], acc[i][6], acc[i][7]);
    }
}

// ---------------------------------------------------------------------------
// Depthwise causal conv (D_CONV=4) + bias + SiLU.  Reads x-half of xz, writes x_in.
// ---------------------------------------------------------------------------
__global__ __launch_bounds__(256) void conv_silu_k(
    const float* __restrict__ xz, const float* __restrict__ Wc,
    const float* __restrict__ bc, float* __restrict__ xin)
{
    int idx = blockIdx.x * 256 + threadIdx.x;        // over 4096*2048
    int c = idx & (D_INNER - 1);
    int ml = idx >> 11;                              // row (b*L + l)
    int l = ml & (LSEQ - 1);
    float acc = bc[c];
    #pragma unroll
    for (int k = 0; k < 4; ++k) {
        int ls = l + k - 3;
        if (ls >= 0)
            acc += xz[(size_t)(ml + k - 3) * (2 * D_INNER) + c] * Wc[k * D_INNER + c];
    }
    float sig = 1.f / (1.f + __expf(-acc));
    xin[(size_t)ml * D_INNER + c] = acc * sig;
}

// ---------------------------------------------------------------------------
// dbc = x_in @ W_xproj   (4096x2048)@(2048x96).  block = (96,4): lane j = col.
// ---------------------------------------------------------------------------
__global__ __launch_bounds__(384) void xproj_k(
    const float* __restrict__ xin, const float* __restrict__ W,
    float* __restrict__ dbc)
{
    int j = threadIdx.x;                       // 0..95
    int m = blockIdx.x * 4 + threadIdx.y;
    const float* xr = xin + (size_t)m * D_INNER;
    float acc = 0.f;
    for (int k = 0; k < D_INNER; k += 4) {
        float4 xv = *reinterpret_cast<const float4*>(xr + k);
        acc += xv.x * W[(k + 0) * 96 + j];
        acc += xv.y * W[(k + 1) * 96 + j];
        acc += xv.z * W[(k + 2) * 96 + j];
        acc += xv.w * W[(k + 3) * 96 + j];
    }
    dbc[(size_t)m * 96 + j] = acc;
}

// ---------------------------------------------------------------------------
// dt = softplus(dbc[:, :64] @ W_dt + b_dt).  Writes STRIDED into the (dead)
// x-half of the xz buffer (stride 4096) to save workspace.
// ---------------------------------------------------------------------------
__global__ __launch_bounds__(256) void dtproj_k(
    const float* __restrict__ dbc, const float* __restrict__ Wdt,
    const float* __restrict__ bdt, float* __restrict__ dtout)
{
    __shared__ float ds_[16][64];
    int tid = threadIdx.x;
    int d = blockIdx.x * 256 + tid;
    int m0 = blockIdx.y * 16;
    #pragma unroll
    for (int jj = 0; jj < 4; ++jj) {
        int e = tid + 256 * jj; int r = e >> 6, c = e & 63;
        ds_[r][c] = dbc[(size_t)(m0 + r) * 96 + c];
    }
    __syncthreads();
    float acc[16] = {};
    #pragma unroll
    for (int k = 0; k < 64; k += 4) {
        float w0 = Wdt[(k + 0) * D_INNER + d];
        float w1 = Wdt[(k + 1) * D_INNER + d];
        float w2 = Wdt[(k + 2) * D_INNER + d];
        float w3 = Wdt[(k + 3) * D_INNER + d];
        #pragma unroll
        for (int i = 0; i < 16; ++i) {
            float4 v = *reinterpret_cast<const float4*>(&ds_[i][k]);
            acc[i] += v.x * w0 + v.y * w1 + v.z * w2 + v.w * w3;
        }
    }
    float b = bdt[d];
    #pragma unroll
    for (int i = 0; i < 16; ++i) {
        float v = acc[i] + b;
        float sp = fmaxf(v, 0.f) + log1pf(__expf(-fabsf(v)));
        dtout[(size_t)(m0 + i) * (2 * D_INNER) + d] = sp;
    }
}

// ---------------------------------------------------------------------------
// Selective scan + gating.  1 lane per (channel, state n); 16 channels/block.
// dt read strided from xz x-half; y*silu(z) written IN-PLACE over x_in.
// ---------------------------------------------------------------------------
__global__ __launch_bounds__(256) void scan_k(
    const float* __restrict__ xzbuf,   // dt at col d, z at col 2048+d
    float* __restrict__ xin,           // in: x_in, out: y_gated (in-place)
    const float* __restrict__ dbc,
    const float* __restrict__ A_log, const float* __restrict__ Dv)
{
    __shared__ float xs[64][16], dts[64][16], Bs[64][16], Cs[64][16], ys[64][16];
    int tid = threadIdx.x;
    int b = blockIdx.x >> 7;                 // 128 blocks per batch
    int c0 = (blockIdx.x & 127) << 4;
    int n = tid & 15, ch = tid >> 4;
    int d = c0 + ch;
    float Adn = -__expf(A_log[d * D_STATE + n]);
    float Dd = Dv[d];
    float state = 0.f;
    size_t base = (size_t)b * LSEQ;

    for (int t0 = 0; t0 < LSEQ; t0 += 64) {
        #pragma unroll
        for (int jj = 0; jj < 4; ++jj) {
            int e = tid + 256 * jj; int r = e >> 4, c = e & 15;
            size_t m = base + t0 + r;
            xs[r][c]  = xin[m * D_INNER + c0 + c];
            dts[r][c] = xzbuf[m * (2 * D_INNER) + c0 + c];
            Bs[r][c]  = dbc[m * 96 + 64 + c];
            Cs[r][c]  = dbc[m * 96 + 80 + c];
        }
        __syncthreads();
        #pragma unroll 4
        for (int t = 0; t < 64; ++t) {
            float dtv = dts[t][ch];
            float xv  = xs[t][ch];
            float arg = dtv * Adn;
            arg = fminf(fmaxf(arg, -10.f), 10.f);
            float dA = __expf(arg);
            float s = state * dA + (xv * dtv) * Bs[t][n];
            state = fminf(fmaxf(s, -10.f), 10.f);
            float p = state * Cs[t][n];
            p += __shfl_xor(p, 1);
            p += __shfl_xor(p, 2);
            p += __shfl_xor(p, 4);
            p += __shfl_xor(p, 8);
            if (n == 0) ys[t][ch] = p + Dd * xv;
        }
        __syncthreads();
        #pragma unroll
        for (int jj = 0; jj < 4; ++jj) {
            int e = tid + 256 * jj; int r = e >> 4, c = e & 15;
            size_t m = base + t0 + r;
            float z = xzbuf[m * (2 * D_INNER) + D_INNER + c0 + c];
            float sz = z / (1.f + __expf(-z));
            xin[m * D_INNER + c0 + c] = ys[r][c] * sz;
        }
        __syncthreads();
    }
}

// ---------------------------------------------------------------------------
extern "C" void kernel_launch(void* const* d_in, const int* in_sizes, int n_in,
                              void* d_out, int out_size, void* d_ws, size_t ws_size,
                              hipStream_t stream)
{
    const float* x       = (const float*)d_in[0];
    const float* W_in    = (const float*)d_in[1];
    const float* W_conv  = (const float*)d_in[2];
    const float* b_conv  = (const float*)d_in[3];
    const float* W_xproj = (const float*)d_in[4];
    const float* W_dt    = (const float*)d_in[5];
    const float* b_dt    = (const float*)d_in[6];
    const float* A_log   = (const float*)d_in[7];
    const float* Dv      = (const float*)d_in[8];
    const float* W_out   = (const float*)d_in[9];
    float* out = (float*)d_out;

    // workspace layout (floats): xz 16.78M | xin 8.39M | dbc 0.39M  => ~102 MB
    float* xz  = (float*)d_ws;
    float* xin = xz + (size_t)M_TOT * 2 * D_INNER;
    float* dbc = xin + (size_t)M_TOT * D_INNER;

    // 1) xz = x @ W_in                     (4096 x 4096 x K=1024)
    gemm_f32<128, 128, 16><<<dim3(32, 32), 256, 0, stream>>>(x, W_in, xz, M_TOT, 2 * D_INNER, D_MODEL);
    // 2) x_in = silu(causal_conv(xz[:, :2048]) + b_conv)
    conv_silu_k<<<(M_TOT * D_INNER) / 256, 256, 0, stream>>>(xz, W_conv, b_conv, xin);
    // 3) dbc = x_in @ W_xproj              (4096 x 96 x K=2048)
    xproj_k<<<M_TOT / 4, dim3(96, 4), 0, stream>>>(xin, W_xproj, dbc);
    // 4) dt = softplus(dbc[:,:64] @ W_dt + b_dt)  -> strided into xz x-half
    dtproj_k<<<dim3(D_INNER / 256, M_TOT / 16), 256, 0, stream>>>(dbc, W_dt, b_dt, xz);
    // 5) selective scan + gating -> y_gated in-place over xin
    scan_k<<<NBATCH * (D_INNER / 16), 256, 0, stream>>>(xz, xin, dbc, A_log, Dv);
    // 6) out = y_gated @ W_out             (4096 x 1024 x K=2048)
    gemm_f32<128, 128, 16><<<dim3(8, 32), 256, 0, stream>>>(xin, W_out, out, M_TOT, D_MODEL, D_INNER);
}

// Round 2
// 1159.644 us; speedup vs baseline: 1.2968x; 1.2968x over previous
//
#include <hip/hip_runtime.h>
#include <math.h>

#define D_MODEL 1024
#define D_INNER 2048
#define D_STATE 16
#define DT_RANK 64
#define LSEQ 2048
#define NBATCH 2
#define M_TOT (NBATCH * LSEQ)   // 4096 rows total

// ---------------------------------------------------------------------------
// fp32 tiled GEMM: C[M,N] = A[M,K] @ B[K,N], all row-major, dims divisible by
// tile. 128x128 block tile, 8x8 per-thread microtile, BK=16, 256 threads.
// ---------------------------------------------------------------------------
template <int BM, int BN, int BK>
__global__ __launch_bounds__(256) void gemm_f32(
    const float* __restrict__ A, const float* __restrict__ B,
    float* __restrict__ C, int M, int N, int K)
{
    __shared__ float As[BK][BM + 4];   // +4 pad keeps 16B alignment, breaks conflicts
    __shared__ float Bs[BK][BN];
    const int tid = threadIdx.x;
    const int m0 = blockIdx.y * BM, n0 = blockIdx.x * BN;
    const int tx = tid & 15, ty = tid >> 4;   // 16x16 thread grid
    float acc[8][8] = {};

    for (int k0 = 0; k0 < K; k0 += BK) {
        #pragma unroll
        for (int j = 0; j < (BM * BK) / (256 * 4); ++j) {
            int i = tid + 256 * j;
            int r = i >> 2, c4 = (i & 3) << 2;
            float4 v = *reinterpret_cast<const float4*>(A + (size_t)(m0 + r) * K + k0 + c4);
            As[c4 + 0][r] = v.x; As[c4 + 1][r] = v.y;
            As[c4 + 2][r] = v.z; As[c4 + 3][r] = v.w;
        }
        #pragma unroll
        for (int j = 0; j < (BK * BN) / (256 * 4); ++j) {
            int i = tid + 256 * j;
            int r = i / (BN / 4), c4 = (i % (BN / 4)) << 2;
            float4 v = *reinterpret_cast<const float4*>(B + (size_t)(k0 + r) * N + n0 + c4);
            *reinterpret_cast<float4*>(&Bs[r][c4]) = v;
        }
        __syncthreads();
        #pragma unroll
        for (int k = 0; k < BK; ++k) {
            float a[8], b[8];
            *reinterpret_cast<float4*>(&a[0]) = *reinterpret_cast<const float4*>(&As[k][ty * 8]);
            *reinterpret_cast<float4*>(&a[4]) = *reinterpret_cast<const float4*>(&As[k][ty * 8 + 4]);
            *reinterpret_cast<float4*>(&b[0]) = *reinterpret_cast<const float4*>(&Bs[k][tx * 8]);
            *reinterpret_cast<float4*>(&b[4]) = *reinterpret_cast<const float4*>(&Bs[k][tx * 8 + 4]);
            #pragma unroll
            for (int i = 0; i < 8; ++i)
                #pragma unroll
                for (int j = 0; j < 8; ++j)
                    acc[i][j] += a[i] * b[j];
        }
        __syncthreads();
    }
    #pragma unroll
    for (int i = 0; i < 8; ++i) {
        size_t row = (size_t)(m0 + ty * 8 + i) * N + n0 + tx * 8;
        *reinterpret_cast<float4*>(C + row)     = make_float4(acc[i][0], acc[i][1], acc[i][2], acc[i][3]);
        *reinterpret_cast<float4*>(C + row + 4) = make_float4(acc[i][4], acc[i][5], acc[i][6], acc[i][7]);
    }
}

// ---------------------------------------------------------------------------
// Depthwise causal conv (D_CONV=4) + bias + SiLU.
// ---------------------------------------------------------------------------
__global__ __launch_bounds__(256) void conv_silu_k(
    const float* __restrict__ xz, const float* __restrict__ Wc,
    const float* __restrict__ bc, float* __restrict__ xin)
{
    int idx = blockIdx.x * 256 + threadIdx.x;
    int c = idx & (D_INNER - 1);
    int ml = idx >> 11;
    int l = ml & (LSEQ - 1);
    float acc = bc[c];
    #pragma unroll
    for (int k = 0; k < 4; ++k) {
        int ls = l + k - 3;
        if (ls >= 0)
            acc += xz[(size_t)(ml + k - 3) * (2 * D_INNER) + c] * Wc[k * D_INNER + c];
    }
    float sig = 1.f / (1.f + __expf(-acc));
    xin[(size_t)ml * D_INNER + c] = acc * sig;
}

// ---------------------------------------------------------------------------
// dbc = x_in @ W_xproj   (4096x2048)@(2048x96)
// ---------------------------------------------------------------------------
__global__ __launch_bounds__(384) void xproj_k(
    const float* __restrict__ xin, const float* __restrict__ W,
    float* __restrict__ dbc)
{
    int j = threadIdx.x;
    int m = blockIdx.x * 4 + threadIdx.y;
    const float* xr = xin + (size_t)m * D_INNER;
    float acc = 0.f;
    for (int k = 0; k < D_INNER; k += 4) {
        float4 xv = *reinterpret_cast<const float4*>(xr + k);
        acc += xv.x * W[(k + 0) * 96 + j];
        acc += xv.y * W[(k + 1) * 96 + j];
        acc += xv.z * W[(k + 2) * 96 + j];
        acc += xv.w * W[(k + 3) * 96 + j];
    }
    dbc[(size_t)m * 96 + j] = acc;
}

// ---------------------------------------------------------------------------
// dt = softplus(dbc[:, :64] @ W_dt + b_dt) -> strided into xz x-half.
// ---------------------------------------------------------------------------
__global__ __launch_bounds__(256) void dtproj_k(
    const float* __restrict__ dbc, const float* __restrict__ Wdt,
    const float* __restrict__ bdt, float* __restrict__ dtout)
{
    __shared__ float ds_[16][64];
    int tid = threadIdx.x;
    int d = blockIdx.x * 256 + tid;
    int m0 = blockIdx.y * 16;
    #pragma unroll
    for (int jj = 0; jj < 4; ++jj) {
        int e = tid + 256 * jj; int r = e >> 6, c = e & 63;
        ds_[r][c] = dbc[(size_t)(m0 + r) * 96 + c];
    }
    __syncthreads();
    float acc[16] = {};
    #pragma unroll
    for (int k = 0; k < 64; k += 4) {
        float w0 = Wdt[(k + 0) * D_INNER + d];
        float w1 = Wdt[(k + 1) * D_INNER + d];
        float w2 = Wdt[(k + 2) * D_INNER + d];
        float w3 = Wdt[(k + 3) * D_INNER + d];
        #pragma unroll
        for (int i = 0; i < 16; ++i) {
            float4 v = *reinterpret_cast<const float4*>(&ds_[i][k]);
            acc[i] += v.x * w0 + v.y * w1 + v.z * w2 + v.w * w3;
        }
    }
    float b = bdt[d];
    #pragma unroll
    for (int i = 0; i < 16; ++i) {
        float v = acc[i] + b;
        float sp = fmaxf(v, 0.f) + log1pf(__expf(-fabsf(v)));
        dtout[(size_t)(m0 + i) * (2 * D_INNER) + d] = sp;
    }
}

// ---------------------------------------------------------------------------
// Selective scan + gating, v2: NO cross-lane ops in the serial loop.
// Lane = (channel, state n). Per step only: state = clamp(fma(state,dA,dtxB));
// p = state*C written to LDS (off the dependency chain). Per-32-step chunk, a
// parallel phase reduces p over n, gates with silu(z), writes y in-place.
// Staging global loads are register-prefetched one chunk ahead.
// LDS ps layout [t][n*17+ch]: write & read patterns both <=2-way conflicts.
// ---------------------------------------------------------------------------
#define SCHUNK 32

__global__ __launch_bounds__(256) void scan_k(
    const float* __restrict__ xzbuf,   // dt at col d, z at col 2048+d
    float* __restrict__ xin,           // in: x_in, out: y_gated (in-place)
    const float* __restrict__ dbc,
    const float* __restrict__ A_log, const float* __restrict__ Dv)
{
    __shared__ float xs[SCHUNK][16], dts[SCHUNK][16], Bs[SCHUNK][16], Cs[SCHUNK][16];
    __shared__ float ps[SCHUNK][16 * 17];   // [t][n*17+ch]
    const int tid = threadIdx.x;
    const int b = blockIdx.x >> 7;
    const int c0 = (blockIdx.x & 127) << 4;
    const int n = tid & 15, ch = tid >> 4;  // ch 0..15
    const int d = c0 + ch;
    const float Adn = -__expf(A_log[d * D_STATE + n]);
    const float Dn = Dv[c0 + n];            // phase-C column == n
    float state = 0.f;
    const size_t base = (size_t)b * LSEQ;

    // phase-C / staging thread mapping: e=tid+256*jj -> row r=ch+16*jj, col n
    float xg[2], dtg[2], Bg[2], Cg[2], zg[2];
    #pragma unroll
    for (int jj = 0; jj < 2; ++jj) {
        size_t m = base + (ch + 16 * jj);
        xg[jj]  = xin[m * D_INNER + c0 + n];
        dtg[jj] = xzbuf[m * (2 * D_INNER) + c0 + n];
        Bg[jj]  = dbc[m * 96 + 64 + n];
        Cg[jj]  = dbc[m * 96 + 80 + n];
    }

    for (int t0 = 0; t0 < LSEQ; t0 += SCHUNK) {
        // commit prefetched staging regs -> LDS
        #pragma unroll
        for (int jj = 0; jj < 2; ++jj) {
            int r = ch + 16 * jj;
            xs[r][n] = xg[jj]; dts[r][n] = dtg[jj];
            Bs[r][n] = Bg[jj]; Cs[r][n] = Cg[jj];
        }
        __syncthreads();

        // prefetch NEXT chunk staging + CURRENT chunk z (latency hides behind B)
        int t1 = (t0 + SCHUNK < LSEQ) ? t0 + SCHUNK : t0;
        #pragma unroll
        for (int jj = 0; jj < 2; ++jj) {
            size_t mn = base + t1 + (ch + 16 * jj);
            size_t mz = base + t0 + (ch + 16 * jj);
            xg[jj]  = xin[mn * D_INNER + c0 + n];
            dtg[jj] = xzbuf[mn * (2 * D_INNER) + c0 + n];
            Bg[jj]  = dbc[mn * 96 + 64 + n];
            Cg[jj]  = dbc[mn * 96 + 80 + n];
            zg[jj]  = xzbuf[mz * (2 * D_INNER) + D_INNER + c0 + n];
        }

        // phase B: serial scan; loop-carried chain = fma+min+max only
        #pragma unroll
        for (int t = 0; t < SCHUNK; ++t) {
            float dtv = dts[t][ch];          // broadcast across n-lanes
            float xv  = xs[t][ch];
            float Bv  = Bs[t][n];
            float Cv  = Cs[t][n];
            float arg = fminf(fmaxf(dtv * Adn, -10.f), 10.f);
            float dA  = __expf(arg);
            float s   = state * dA + dtv * xv * Bv;
            state     = fminf(fmaxf(s, -10.f), 10.f);
            ps[t][n * 17 + ch] = state * Cv;
        }
        __syncthreads();

        // phase C: reduce over n, gate with silu(z), write y in-place
        #pragma unroll
        for (int jj = 0; jj < 2; ++jj) {
            int r = ch + 16 * jj;
            size_t m = base + t0 + r;
            float sum = 0.f;
            #pragma unroll
            for (int k = 0; k < 16; ++k)
                sum += ps[r][k * 17 + n];
            float yv = sum + Dn * xs[r][n];
            float z  = zg[jj];
            float sz = z / (1.f + __expf(-z));
            xin[m * D_INNER + c0 + n] = yv * sz;
        }
        __syncthreads();
    }
}

// ---------------------------------------------------------------------------
extern "C" void kernel_launch(void* const* d_in, const int* in_sizes, int n_in,
                              void* d_out, int out_size, void* d_ws, size_t ws_size,
                              hipStream_t stream)
{
    const float* x       = (const float*)d_in[0];
    const float* W_in    = (const float*)d_in[1];
    const float* W_conv  = (const float*)d_in[2];
    const float* b_conv  = (const float*)d_in[3];
    const float* W_xproj = (const float*)d_in[4];
    const float* W_dt    = (const float*)d_in[5];
    const float* b_dt    = (const float*)d_in[6];
    const float* A_log   = (const float*)d_in[7];
    const float* Dv      = (const float*)d_in[8];
    const float* W_out   = (const float*)d_in[9];
    float* out = (float*)d_out;

    float* xz  = (float*)d_ws;
    float* xin = xz + (size_t)M_TOT * 2 * D_INNER;
    float* dbc = xin + (size_t)M_TOT * D_INNER;

    gemm_f32<128, 128, 16><<<dim3(32, 32), 256, 0, stream>>>(x, W_in, xz, M_TOT, 2 * D_INNER, D_MODEL);
    conv_silu_k<<<(M_TOT * D_INNER) / 256, 256, 0, stream>>>(xz, W_conv, b_conv, xin);
    xproj_k<<<M_TOT / 4, dim3(96, 4), 0, stream>>>(xin, W_xproj, dbc);
    dtproj_k<<<dim3(D_INNER / 256, M_TOT / 16), 256, 0, stream>>>(dbc, W_dt, b_dt, xz);
    scan_k<<<NBATCH * (D_INNER / 16), 256, 0, stream>>>(xz, xin, dbc, A_log, Dv);
    gemm_f32<128, 128, 16><<<dim3(8, 32), 256, 0, stream>>>(xin, W_out, out, M_TOT, D_MODEL, D_INNER);
}

// Round 3
// 734.554 us; speedup vs baseline: 2.0472x; 1.5787x over previous
//
#include <hip/hip_runtime.h>
#include <math.h>

#define D_MODEL 1024
#define D_INNER 2048
#define D_STATE 16
#define DT_RANK 64
#define LSEQ 2048
#define NBATCH 2
#define M_TOT (NBATCH * LSEQ)   // 4096 rows total

typedef unsigned short ushort_t;
typedef unsigned int uint_t;
typedef __attribute__((ext_vector_type(8))) short bf16x8;
typedef __attribute__((ext_vector_type(4))) float f32x4;

__device__ __forceinline__ ushort_t f2bf_rne(float f) {
    uint_t u = __float_as_uint(f);
    u += 0x7fffu + ((u >> 16) & 1u);
    return (ushort_t)(u >> 16);
}
__device__ __forceinline__ float bf2f(ushort_t h) {
    return __uint_as_float(((uint_t)h) << 16);
}

// ---------------------------------------------------------------------------
// Split-bf16 MFMA GEMM: C[M,N] fp32 = (Ah+Al)[M,K] @ (Bh+Bl)[K,N], where B is
// stored pre-transposed as BT[N][K] bf16. 3-term: AhBh + AlBh + AhBl.
// 128x128 tile, 4 waves, each wave 64x64 (4x4 of 16x16x32 MFMA), BK=32.
// Staging via global_load_lds width=16; LDS chunk swizzle (row>>1)&3 applied
// on the GLOBAL source address so frag ds_read_b128 is bank-uniform.
// ---------------------------------------------------------------------------
__global__ __launch_bounds__(256) void gemm_bf16s(
    const ushort_t* __restrict__ Ah, const ushort_t* __restrict__ Al,
    const ushort_t* __restrict__ BTh, const ushort_t* __restrict__ BTl,
    float* __restrict__ C, int M, int N, int K)
{
    __shared__ __align__(16) ushort_t smem[4 * 128 * 32];   // Ah|Al|Bh|Bl tiles
    ushort_t* sA[2] = { smem,            smem + 4096 };
    ushort_t* sB[2] = { smem + 8192,     smem + 12288 };
    const int tid = threadIdx.x;
    const int lane = tid & 63;
    const int m0 = blockIdx.y * 128, n0 = blockIdx.x * 128;
    const int wave = tid >> 6;
    const int mw = (wave & 1) * 64, nw = (wave >> 1) * 64;
    const int fm = lane & 15, fk = lane >> 4;
    const int swz = fk ^ ((fm >> 1) & 3);      // frag chunk after swizzle

    f32x4 acc[4][4] = {};

    // staging decomposition: element e = j*256+tid -> tile row r=e>>2, phys chunk cp=e&3
    const int r_st0 = tid >> 2, cp0 = tid & 3;
    const int r_st1 = (256 + tid) >> 2, cp1 = tid & 3;
    const int cl0 = cp0 ^ ((r_st0 >> 1) & 3);  // logical chunk to fetch
    const int cl1 = cp1 ^ ((r_st1 >> 1) & 3);
    // wave-uniform LDS byte base for each of the two calls per tile
    const int ldsb0 = (tid & ~63) * 16;             // (elements e base)*16B
    const int ldsb1 = (256 + (tid & ~63)) * 16;

    for (int k0 = 0; k0 < K; k0 += 32) {
        __syncthreads();
        // ---- stage 4 tiles (Ah, Al, BTh, BTl), 2 calls each ----
        {
            size_t ga0 = (size_t)(m0 + r_st0) * K + k0 + cl0 * 8;
            size_t ga1 = (size_t)(m0 + r_st1) * K + k0 + cl1 * 8;
            size_t gb0 = (size_t)(n0 + r_st0) * K + k0 + cl0 * 8;
            size_t gb1 = (size_t)(n0 + r_st1) * K + k0 + cl1 * 8;
            __builtin_amdgcn_global_load_lds(
                (const __attribute__((address_space(1))) void*)(Ah + ga0),
                (__attribute__((address_space(3))) void*)((char*)sA[0] + ldsb0), 16, 0, 0);
            __builtin_amdgcn_global_load_lds(
                (const __attribute__((address_space(1))) void*)(Ah + ga1),
                (__attribute__((address_space(3))) void*)((char*)sA[0] + ldsb1), 16, 0, 0);
            __builtin_amdgcn_global_load_lds(
                (const __attribute__((address_space(1))) void*)(Al + ga0),
                (__attribute__((address_space(3))) void*)((char*)sA[1] + ldsb0), 16, 0, 0);
            __builtin_amdgcn_global_load_lds(
                (const __attribute__((address_space(1))) void*)(Al + ga1),
                (__attribute__((address_space(3))) void*)((char*)sA[1] + ldsb1), 16, 0, 0);
            __builtin_amdgcn_global_load_lds(
                (const __attribute__((address_space(1))) void*)(BTh + gb0),
                (__attribute__((address_space(3))) void*)((char*)sB[0] + ldsb0), 16, 0, 0);
            __builtin_amdgcn_global_load_lds(
                (const __attribute__((address_space(1))) void*)(BTh + gb1),
                (__attribute__((address_space(3))) void*)((char*)sB[0] + ldsb1), 16, 0, 0);
            __builtin_amdgcn_global_load_lds(
                (const __attribute__((address_space(1))) void*)(BTl + gb0),
                (__attribute__((address_space(3))) void*)((char*)sB[1] + ldsb0), 16, 0, 0);
            __builtin_amdgcn_global_load_lds(
                (const __attribute__((address_space(1))) void*)(BTl + gb1),
                (__attribute__((address_space(3))) void*)((char*)sB[1] + ldsb1), 16, 0, 0);
        }
        __syncthreads();

        // ---- frag loads (b128, bank-uniform via swz) ----
        bf16x8 fAh[4], fAl[4], fBh[4], fBl[4];
        #pragma unroll
        for (int t = 0; t < 4; ++t) {
            int ra = (mw + t * 16 + fm) * 32 + swz * 8;
            int rb = (nw + t * 16 + fm) * 32 + swz * 8;
            fAh[t] = *reinterpret_cast<const bf16x8*>(&sA[0][ra]);
            fAl[t] = *reinterpret_cast<const bf16x8*>(&sA[1][ra]);
            fBh[t] = *reinterpret_cast<const bf16x8*>(&sB[0][rb]);
            fBl[t] = *reinterpret_cast<const bf16x8*>(&sB[1][rb]);
        }
        // ---- 48 MFMAs: AhBh + AlBh + AhBl ----
        #pragma unroll
        for (int i = 0; i < 4; ++i)
            #pragma unroll
            for (int j = 0; j < 4; ++j) {
                acc[i][j] = __builtin_amdgcn_mfma_f32_16x16x32_bf16(fAh[i], fBh[j], acc[i][j], 0, 0, 0);
                acc[i][j] = __builtin_amdgcn_mfma_f32_16x16x32_bf16(fAl[i], fBh[j], acc[i][j], 0, 0, 0);
                acc[i][j] = __builtin_amdgcn_mfma_f32_16x16x32_bf16(fAh[i], fBl[j], acc[i][j], 0, 0, 0);
            }
    }

    // epilogue: C/D layout col=lane&15, row=(lane>>4)*4+reg
    #pragma unroll
    for (int i = 0; i < 4; ++i) {
        int row0 = m0 + mw + i * 16 + fk * 4;
        #pragma unroll
        for (int j = 0; j < 4; ++j) {
            int col = n0 + nw + j * 16 + fm;
            #pragma unroll
            for (int r = 0; r < 4; ++r)
                C[(size_t)(row0 + r) * N + col] = acc[i][j][r];
        }
    }
}

// ---------------------------------------------------------------------------
// x -> (xh, xl) bf16 split, elementwise (float4 / ushort4).
// ---------------------------------------------------------------------------
__global__ __launch_bounds__(256) void cast_hl_k(
    const float* __restrict__ X, ushort_t* __restrict__ Xh, ushort_t* __restrict__ Xl)
{
    int i4 = (blockIdx.x * 256 + threadIdx.x) * 4;
    float4 v = *reinterpret_cast<const float4*>(X + i4);
    ushort_t h[4], l[4];
    float vv[4] = { v.x, v.y, v.z, v.w };
    #pragma unroll
    for (int k = 0; k < 4; ++k) {
        h[k] = f2bf_rne(vv[k]);
        l[k] = f2bf_rne(vv[k] - bf2f(h[k]));
    }
    *reinterpret_cast<ushort2*>(Xh + i4)     = make_ushort2(h[0], h[1]);
    *reinterpret_cast<ushort2*>(Xh + i4 + 2) = make_ushort2(h[2], h[3]);
    *reinterpret_cast<ushort2*>(Xl + i4)     = make_ushort2(l[0], l[1]);
    *reinterpret_cast<ushort2*>(Xl + i4 + 2) = make_ushort2(l[2], l[3]);
}

// ---------------------------------------------------------------------------
// W[K][N] fp32 -> WT[N][K] bf16 hi/lo (tiled transpose).
// ---------------------------------------------------------------------------
__global__ __launch_bounds__(256) void transpose_cast_k(
    const float* __restrict__ W, ushort_t* __restrict__ Th, ushort_t* __restrict__ Tl,
    int K, int N)
{
    __shared__ float tile[32][33];
    int n0 = blockIdx.x * 32, k0 = blockIdx.y * 32;
    int tx = threadIdx.x & 31, ty = threadIdx.x >> 5;   // 32 x 8
    #pragma unroll
    for (int i = 0; i < 32; i += 8)
        tile[ty + i][tx] = W[(size_t)(k0 + ty + i) * N + n0 + tx];
    __syncthreads();
    #pragma unroll
    for (int i = 0; i < 32; i += 8) {
        float v = tile[tx][ty + i];                     // W[k0+tx][n0+ty+i]
        ushort_t h = f2bf_rne(v);
        ushort_t l = f2bf_rne(v - bf2f(h));
        size_t o = (size_t)(n0 + ty + i) * K + k0 + tx;
        Th[o] = h; Tl[o] = l;
    }
}

// ---------------------------------------------------------------------------
// Depthwise causal conv (D_CONV=4) + bias + SiLU.
// ---------------------------------------------------------------------------
__global__ __launch_bounds__(256) void conv_silu_k(
    const float* __restrict__ xz, const float* __restrict__ Wc,
    const float* __restrict__ bc, float* __restrict__ xin)
{
    int idx = blockIdx.x * 256 + threadIdx.x;
    int c = idx & (D_INNER - 1);
    int ml = idx >> 11;
    int l = ml & (LSEQ - 1);
    float acc = bc[c];
    #pragma unroll
    for (int k = 0; k < 4; ++k) {
        int ls = l + k - 3;
        if (ls >= 0)
            acc += xz[(size_t)(ml + k - 3) * (2 * D_INNER) + c] * Wc[k * D_INNER + c];
    }
    float sig = 1.f / (1.f + __expf(-acc));
    xin[(size_t)ml * D_INNER + c] = acc * sig;
}

// ---------------------------------------------------------------------------
// dbc = x_in @ W_xproj   (4096x2048)@(2048x96)
// ---------------------------------------------------------------------------
__global__ __launch_bounds__(384) void xproj_k(
    const float* __restrict__ xin, const float* __restrict__ W,
    float* __restrict__ dbc)
{
    int j = threadIdx.x;
    int m = blockIdx.x * 4 + threadIdx.y;
    const float* xr = xin + (size_t)m * D_INNER;
    float acc = 0.f;
    for (int k = 0; k < D_INNER; k += 4) {
        float4 xv = *reinterpret_cast<const float4*>(xr + k);
        acc += xv.x * W[(k + 0) * 96 + j];
        acc += xv.y * W[(k + 1) * 96 + j];
        acc += xv.z * W[(k + 2) * 96 + j];
        acc += xv.w * W[(k + 3) * 96 + j];
    }
    dbc[(size_t)m * 96 + j] = acc;
}

// ---------------------------------------------------------------------------
// dt = softplus(dbc[:, :64] @ W_dt + b_dt) -> strided into xz x-half.
// ---------------------------------------------------------------------------
__global__ __launch_bounds__(256) void dtproj_k(
    const float* __restrict__ dbc, const float* __restrict__ Wdt,
    const float* __restrict__ bdt, float* __restrict__ dtout)
{
    __shared__ float ds_[16][64];
    int tid = threadIdx.x;
    int d = blockIdx.x * 256 + tid;
    int m0 = blockIdx.y * 16;
    #pragma unroll
    for (int jj = 0; jj < 4; ++jj) {
        int e = tid + 256 * jj; int r = e >> 6, c = e & 63;
        ds_[r][c] = dbc[(size_t)(m0 + r) * 96 + c];
    }
    __syncthreads();
    float acc[16] = {};
    #pragma unroll
    for (int k = 0; k < 64; k += 4) {
        float w0 = Wdt[(k + 0) * D_INNER + d];
        float w1 = Wdt[(k + 1) * D_INNER + d];
        float w2 = Wdt[(k + 2) * D_INNER + d];
        float w3 = Wdt[(k + 3) * D_INNER + d];
        #pragma unroll
        for (int i = 0; i < 16; ++i) {
            float4 v = *reinterpret_cast<const float4*>(&ds_[i][k]);
            acc[i] += v.x * w0 + v.y * w1 + v.z * w2 + v.w * w3;
        }
    }
    float b = bdt[d];
    #pragma unroll
    for (int i = 0; i < 16; ++i) {
        float v = acc[i] + b;
        float sp = fmaxf(v, 0.f) + log1pf(__expf(-fabsf(v)));
        dtout[(size_t)(m0 + i) * (2 * D_INNER) + d] = sp;
    }
}

// ---------------------------------------------------------------------------
// Selective scan + gating.  Writes y_gated as bf16 hi/lo (out-proj A operand).
// ---------------------------------------------------------------------------
#define SCHUNK 32

__global__ __launch_bounds__(256) void scan_k(
    const float* __restrict__ xzbuf,   // dt at col d, z at col 2048+d
    const float* __restrict__ xin,     // x_in
    const float* __restrict__ dbc,
    const float* __restrict__ A_log, const float* __restrict__ Dv,
    ushort_t* __restrict__ Yh, ushort_t* __restrict__ Yl)
{
    __shared__ float xs[SCHUNK][16], dts[SCHUNK][16], Bs[SCHUNK][16], Cs[SCHUNK][16];
    __shared__ float ps[SCHUNK][16 * 17];   // [t][n*17+ch]
    const int tid = threadIdx.x;
    const int b = blockIdx.x >> 7;
    const int c0 = (blockIdx.x & 127) << 4;
    const int n = tid & 15, ch = tid >> 4;
    const int d = c0 + ch;
    const float Adn = -__expf(A_log[d * D_STATE + n]);
    const float Dn = Dv[c0 + n];
    float state = 0.f;
    const size_t base = (size_t)b * LSEQ;

    float xg[2], dtg[2], Bg[2], Cg[2], zg[2];
    #pragma unroll
    for (int jj = 0; jj < 2; ++jj) {
        size_t m = base + (ch + 16 * jj);
        xg[jj]  = xin[m * D_INNER + c0 + n];
        dtg[jj] = xzbuf[m * (2 * D_INNER) + c0 + n];
        Bg[jj]  = dbc[m * 96 + 64 + n];
        Cg[jj]  = dbc[m * 96 + 80 + n];
    }

    for (int t0 = 0; t0 < LSEQ; t0 += SCHUNK) {
        #pragma unroll
        for (int jj = 0; jj < 2; ++jj) {
            int r = ch + 16 * jj;
            xs[r][n] = xg[jj]; dts[r][n] = dtg[jj];
            Bs[r][n] = Bg[jj]; Cs[r][n] = Cg[jj];
        }
        __syncthreads();

        int t1 = (t0 + SCHUNK < LSEQ) ? t0 + SCHUNK : t0;
        #pragma unroll
        for (int jj = 0; jj < 2; ++jj) {
            size_t mn = base + t1 + (ch + 16 * jj);
            size_t mz = base + t0 + (ch + 16 * jj);
            xg[jj]  = xin[mn * D_INNER + c0 + n];
            dtg[jj] = xzbuf[mn * (2 * D_INNER) + c0 + n];
            Bg[jj]  = dbc[mn * 96 + 64 + n];
            Cg[jj]  = dbc[mn * 96 + 80 + n];
            zg[jj]  = xzbuf[mz * (2 * D_INNER) + D_INNER + c0 + n];
        }

        #pragma unroll
        for (int t = 0; t < SCHUNK; ++t) {
            float dtv = dts[t][ch];
            float xv  = xs[t][ch];
            float Bv  = Bs[t][n];
            float Cv  = Cs[t][n];
            float arg = fminf(fmaxf(dtv * Adn, -10.f), 10.f);
            float dA  = __expf(arg);
            float s   = state * dA + dtv * xv * Bv;
            state     = fminf(fmaxf(s, -10.f), 10.f);
            ps[t][n * 17 + ch] = state * Cv;
        }
        __syncthreads();

        #pragma unroll
        for (int jj = 0; jj < 2; ++jj) {
            int r = ch + 16 * jj;
            size_t m = base + t0 + r;
            float sum = 0.f;
            #pragma unroll
            for (int k = 0; k < 16; ++k)
                sum += ps[r][k * 17 + n];
            float yv = sum + Dn * xs[r][n];
            float z  = zg[jj];
            float sz = z / (1.f + __expf(-z));
            float val = yv * sz;
            ushort_t h = f2bf_rne(val);
            ushort_t l = f2bf_rne(val - bf2f(h));
            Yh[m * D_INNER + c0 + n] = h;
            Yl[m * D_INNER + c0 + n] = l;
        }
        __syncthreads();
    }
}

// ---------------------------------------------------------------------------
extern "C" void kernel_launch(void* const* d_in, const int* in_sizes, int n_in,
                              void* d_out, int out_size, void* d_ws, size_t ws_size,
                              hipStream_t stream)
{
    const float* x       = (const float*)d_in[0];
    const float* W_in    = (const float*)d_in[1];
    const float* W_conv  = (const float*)d_in[2];
    const float* b_conv  = (const float*)d_in[3];
    const float* W_xproj = (const float*)d_in[4];
    const float* W_dt    = (const float*)d_in[5];
    const float* b_dt    = (const float*)d_in[6];
    const float* A_log   = (const float*)d_in[7];
    const float* Dv      = (const float*)d_in[8];
    const float* W_out   = (const float*)d_in[9];
    float* out = (float*)d_out;

    // fp32 region
    float* xz  = (float*)d_ws;                              // 16.78M f
    float* xin = xz + (size_t)M_TOT * 2 * D_INNER;          // 8.39M f
    float* dbc = xin + (size_t)M_TOT * D_INNER;             // 0.39M f
    // bf16 region
    ushort_t* xh     = (ushort_t*)(dbc + (size_t)M_TOT * 96);
    ushort_t* xl     = xh + (size_t)M_TOT * D_MODEL;
    ushort_t* WinTh  = xl + (size_t)M_TOT * D_MODEL;        // [4096][1024]
    ushort_t* WinTl  = WinTh + (size_t)2 * D_INNER * D_MODEL;
    ushort_t* WoutTh = WinTl + (size_t)2 * D_INNER * D_MODEL; // [1024][2048]
    ushort_t* WoutTl = WoutTh + (size_t)D_MODEL * D_INNER;
    ushort_t* yh     = WoutTl + (size_t)D_MODEL * D_INNER;  // [4096][2048]
    ushort_t* yl     = yh + (size_t)M_TOT * D_INNER;

    // precompute: casts + weight transposes
    cast_hl_k<<<(M_TOT * D_MODEL) / 1024, 256, 0, stream>>>(x, xh, xl);
    transpose_cast_k<<<dim3((2 * D_INNER) / 32, D_MODEL / 32), 256, 0, stream>>>(
        W_in, WinTh, WinTl, D_MODEL, 2 * D_INNER);
    transpose_cast_k<<<dim3(D_MODEL / 32, D_INNER / 32), 256, 0, stream>>>(
        W_out, WoutTh, WoutTl, D_INNER, D_MODEL);

    // 1) xz = x @ W_in          (M=4096, N=4096, K=1024)
    gemm_bf16s<<<dim3(32, 32), 256, 0, stream>>>(xh, xl, WinTh, WinTl, xz,
                                                 M_TOT, 2 * D_INNER, D_MODEL);
    // 2) conv + silu
    conv_silu_k<<<(M_TOT * D_INNER) / 256, 256, 0, stream>>>(xz, W_conv, b_conv, xin);
    // 3) dbc
    xproj_k<<<M_TOT / 4, dim3(96, 4), 0, stream>>>(xin, W_xproj, dbc);
    // 4) dt -> xz x-half (strided)
    dtproj_k<<<dim3(D_INNER / 256, M_TOT / 16), 256, 0, stream>>>(dbc, W_dt, b_dt, xz);
    // 5) scan + gate -> yh/yl bf16
    scan_k<<<NBATCH * (D_INNER / 16), 256, 0, stream>>>(xz, xin, dbc, A_log, Dv, yh, yl);
    // 6) out = y @ W_out        (M=4096, N=1024, K=2048)
    gemm_bf16s<<<dim3(8, 32), 256, 0, stream>>>(yh, yl, WoutTh, WoutTl, out,
                                                M_TOT, D_MODEL, D_INNER);
}

// Round 4
// 657.831 us; speedup vs baseline: 2.2860x; 1.1166x over previous
//
#include <hip/hip_runtime.h>
#include <math.h>

#define D_MODEL 1024
#define D_INNER 2048
#define D_STATE 16
#define DT_RANK 64
#define LSEQ 2048
#define NBATCH 2
#define M_TOT (NBATCH * LSEQ)   // 4096 rows total
#define DBC_STRIDE 128          // padded xproj output stride

typedef unsigned short ushort_t;
typedef unsigned int uint_t;
typedef __attribute__((ext_vector_type(8))) short bf16x8;
typedef __attribute__((ext_vector_type(4))) float f32x4;

__device__ __forceinline__ ushort_t f2bf_rne(float f) {
    uint_t u = __float_as_uint(f);
    u += 0x7fffu + ((u >> 16) & 1u);
    return (ushort_t)(u >> 16);
}
__device__ __forceinline__ float bf2f(ushort_t h) {
    return __uint_as_float(((uint_t)h) << 16);
}

// ---------------------------------------------------------------------------
// Split-bf16 MFMA GEMM: C[M,N] fp32 = (Ah+Al)[M,K] @ (Bh+Bl)[K,N], B stored
// pre-transposed as BT[N][K] bf16. 3-term: AhBh + AlBh + AhBl.
// 128x128 tile, 4 waves, each 64x64 (4x4 of 16x16x32 MFMA), BK=32.
// global_load_lds width=16; chunk swizzle on the GLOBAL source address.
// ---------------------------------------------------------------------------
__global__ __launch_bounds__(256) void gemm_bf16s(
    const ushort_t* __restrict__ Ah, const ushort_t* __restrict__ Al,
    const ushort_t* __restrict__ BTh, const ushort_t* __restrict__ BTl,
    float* __restrict__ C, int M, int N, int K)
{
    __shared__ __align__(16) ushort_t smem[4 * 128 * 32];   // Ah|Al|Bh|Bl tiles
    ushort_t* sA[2] = { smem,            smem + 4096 };
    ushort_t* sB[2] = { smem + 8192,     smem + 12288 };
    const int tid = threadIdx.x;
    const int lane = tid & 63;
    const int m0 = blockIdx.y * 128, n0 = blockIdx.x * 128;
    const int wave = tid >> 6;
    const int mw = (wave & 1) * 64, nw = (wave >> 1) * 64;
    const int fm = lane & 15, fk = lane >> 4;
    const int swz = fk ^ ((fm >> 1) & 3);

    f32x4 acc[4][4] = {};

    const int r_st0 = tid >> 2, cp0 = tid & 3;
    const int r_st1 = (256 + tid) >> 2, cp1 = tid & 3;
    const int cl0 = cp0 ^ ((r_st0 >> 1) & 3);
    const int cl1 = cp1 ^ ((r_st1 >> 1) & 3);
    const int ldsb0 = (tid & ~63) * 16;
    const int ldsb1 = (256 + (tid & ~63)) * 16;

    for (int k0 = 0; k0 < K; k0 += 32) {
        __syncthreads();
        {
            size_t ga0 = (size_t)(m0 + r_st0) * K + k0 + cl0 * 8;
            size_t ga1 = (size_t)(m0 + r_st1) * K + k0 + cl1 * 8;
            size_t gb0 = (size_t)(n0 + r_st0) * K + k0 + cl0 * 8;
            size_t gb1 = (size_t)(n0 + r_st1) * K + k0 + cl1 * 8;
            __builtin_amdgcn_global_load_lds(
                (const __attribute__((address_space(1))) void*)(Ah + ga0),
                (__attribute__((address_space(3))) void*)((char*)sA[0] + ldsb0), 16, 0, 0);
            __builtin_amdgcn_global_load_lds(
                (const __attribute__((address_space(1))) void*)(Ah + ga1),
                (__attribute__((address_space(3))) void*)((char*)sA[0] + ldsb1), 16, 0, 0);
            __builtin_amdgcn_global_load_lds(
                (const __attribute__((address_space(1))) void*)(Al + ga0),
                (__attribute__((address_space(3))) void*)((char*)sA[1] + ldsb0), 16, 0, 0);
            __builtin_amdgcn_global_load_lds(
                (const __attribute__((address_space(1))) void*)(Al + ga1),
                (__attribute__((address_space(3))) void*)((char*)sA[1] + ldsb1), 16, 0, 0);
            __builtin_amdgcn_global_load_lds(
                (const __attribute__((address_space(1))) void*)(BTh + gb0),
                (__attribute__((address_space(3))) void*)((char*)sB[0] + ldsb0), 16, 0, 0);
            __builtin_amdgcn_global_load_lds(
                (const __attribute__((address_space(1))) void*)(BTh + gb1),
                (__attribute__((address_space(3))) void*)((char*)sB[0] + ldsb1), 16, 0, 0);
            __builtin_amdgcn_global_load_lds(
                (const __attribute__((address_space(1))) void*)(BTl + gb0),
                (__attribute__((address_space(3))) void*)((char*)sB[1] + ldsb0), 16, 0, 0);
            __builtin_amdgcn_global_load_lds(
                (const __attribute__((address_space(1))) void*)(BTl + gb1),
                (__attribute__((address_space(3))) void*)((char*)sB[1] + ldsb1), 16, 0, 0);
        }
        __syncthreads();

        bf16x8 fAh[4], fAl[4], fBh[4], fBl[4];
        #pragma unroll
        for (int t = 0; t < 4; ++t) {
            int ra = (mw + t * 16 + fm) * 32 + swz * 8;
            int rb = (nw + t * 16 + fm) * 32 + swz * 8;
            fAh[t] = *reinterpret_cast<const bf16x8*>(&sA[0][ra]);
            fAl[t] = *reinterpret_cast<const bf16x8*>(&sA[1][ra]);
            fBh[t] = *reinterpret_cast<const bf16x8*>(&sB[0][rb]);
            fBl[t] = *reinterpret_cast<const bf16x8*>(&sB[1][rb]);
        }
        #pragma unroll
        for (int i = 0; i < 4; ++i)
            #pragma unroll
            for (int j = 0; j < 4; ++j) {
                acc[i][j] = __builtin_amdgcn_mfma_f32_16x16x32_bf16(fAh[i], fBh[j], acc[i][j], 0, 0, 0);
                acc[i][j] = __builtin_amdgcn_mfma_f32_16x16x32_bf16(fAl[i], fBh[j], acc[i][j], 0, 0, 0);
                acc[i][j] = __builtin_amdgcn_mfma_f32_16x16x32_bf16(fAh[i], fBl[j], acc[i][j], 0, 0, 0);
            }
    }

    #pragma unroll
    for (int i = 0; i < 4; ++i) {
        int row0 = m0 + mw + i * 16 + fk * 4;
        #pragma unroll
        for (int j = 0; j < 4; ++j) {
            int col = n0 + nw + j * 16 + fm;
            #pragma unroll
            for (int r = 0; r < 4; ++r)
                C[(size_t)(row0 + r) * N + col] = acc[i][j][r];
        }
    }
}

// ---------------------------------------------------------------------------
// x -> (xh, xl) bf16 split, elementwise.
// ---------------------------------------------------------------------------
__global__ __launch_bounds__(256) void cast_hl_k(
    const float* __restrict__ X, ushort_t* __restrict__ Xh, ushort_t* __restrict__ Xl)
{
    int i4 = (blockIdx.x * 256 + threadIdx.x) * 4;
    float4 v = *reinterpret_cast<const float4*>(X + i4);
    ushort_t h[4], l[4];
    float vv[4] = { v.x, v.y, v.z, v.w };
    #pragma unroll
    for (int k = 0; k < 4; ++k) {
        h[k] = f2bf_rne(vv[k]);
        l[k] = f2bf_rne(vv[k] - bf2f(h[k]));
    }
    *reinterpret_cast<ushort2*>(Xh + i4)     = make_ushort2(h[0], h[1]);
    *reinterpret_cast<ushort2*>(Xh + i4 + 2) = make_ushort2(h[2], h[3]);
    *reinterpret_cast<ushort2*>(Xl + i4)     = make_ushort2(l[0], l[1]);
    *reinterpret_cast<ushort2*>(Xl + i4 + 2) = make_ushort2(l[2], l[3]);
}

// ---------------------------------------------------------------------------
// W[K][N] fp32 -> WT[N][K] bf16 hi/lo (tiled transpose, exact dims).
// ---------------------------------------------------------------------------
__global__ __launch_bounds__(256) void transpose_cast_k(
    const float* __restrict__ W, ushort_t* __restrict__ Th, ushort_t* __restrict__ Tl,
    int K, int N)
{
    __shared__ float tile[32][33];
    int n0 = blockIdx.x * 32, k0 = blockIdx.y * 32;
    int tx = threadIdx.x & 31, ty = threadIdx.x >> 5;
    #pragma unroll
    for (int i = 0; i < 32; i += 8)
        tile[ty + i][tx] = W[(size_t)(k0 + ty + i) * N + n0 + tx];
    __syncthreads();
    #pragma unroll
    for (int i = 0; i < 32; i += 8) {
        float v = tile[tx][ty + i];
        ushort_t h = f2bf_rne(v);
        ushort_t l = f2bf_rne(v - bf2f(h));
        size_t o = (size_t)(n0 + ty + i) * K + k0 + tx;
        Th[o] = h; Tl[o] = l;
    }
}

// ---------------------------------------------------------------------------
// W[K][N] fp32 -> WT[Npad][K] bf16 hi/lo, zero-padded rows N..Npad.
// ---------------------------------------------------------------------------
__global__ __launch_bounds__(256) void transpose_cast_pad_k(
    const float* __restrict__ W, ushort_t* __restrict__ Th, ushort_t* __restrict__ Tl,
    int K, int N)
{
    __shared__ float tile[32][33];
    int n0 = blockIdx.x * 32, k0 = blockIdx.y * 32;
    int tx = threadIdx.x & 31, ty = threadIdx.x >> 5;
    #pragma unroll
    for (int i = 0; i < 32; i += 8)
        tile[ty + i][tx] = (n0 + tx < N) ? W[(size_t)(k0 + ty + i) * N + n0 + tx] : 0.f;
    __syncthreads();
    #pragma unroll
    for (int i = 0; i < 32; i += 8) {
        float v = tile[tx][ty + i];
        ushort_t h = f2bf_rne(v);
        ushort_t l = f2bf_rne(v - bf2f(h));
        size_t o = (size_t)(n0 + ty + i) * K + k0 + tx;
        Th[o] = h; Tl[o] = l;
    }
}

// ---------------------------------------------------------------------------
// Depthwise causal conv (D_CONV=4) + bias + SiLU -> x_in as bf16 hi/lo.
// ---------------------------------------------------------------------------
__global__ __launch_bounds__(256) void conv_silu_k(
    const float* __restrict__ xz, const float* __restrict__ Wc,
    const float* __restrict__ bc, ushort_t* __restrict__ xinh,
    ushort_t* __restrict__ xinl)
{
    int idx = blockIdx.x * 256 + threadIdx.x;
    int c = idx & (D_INNER - 1);
    int ml = idx >> 11;
    int l = ml & (LSEQ - 1);
    float acc = bc[c];
    #pragma unroll
    for (int k = 0; k < 4; ++k) {
        int ls = l + k - 3;
        if (ls >= 0)
            acc += xz[(size_t)(ml + k - 3) * (2 * D_INNER) + c] * Wc[k * D_INNER + c];
    }
    float sig = 1.f / (1.f + __expf(-acc));
    float sv = acc * sig;
    ushort_t h = f2bf_rne(sv);
    ushort_t lo = f2bf_rne(sv - bf2f(h));
    size_t o = (size_t)ml * D_INNER + c;
    xinh[o] = h; xinl[o] = lo;
}

// ---------------------------------------------------------------------------
// dt = softplus(dbc[:, :64] @ W_dt + b_dt) -> strided into xz x-half.
// dbc stride = DBC_STRIDE.
// ---------------------------------------------------------------------------
__global__ __launch_bounds__(256) void dtproj_k(
    const float* __restrict__ dbc, const float* __restrict__ Wdt,
    const float* __restrict__ bdt, float* __restrict__ dtout)
{
    __shared__ float ds_[16][64];
    int tid = threadIdx.x;
    int d = blockIdx.x * 256 + tid;
    int m0 = blockIdx.y * 16;
    #pragma unroll
    for (int jj = 0; jj < 4; ++jj) {
        int e = tid + 256 * jj; int r = e >> 6, c = e & 63;
        ds_[r][c] = dbc[(size_t)(m0 + r) * DBC_STRIDE + c];
    }
    __syncthreads();
    float acc[16] = {};
    #pragma unroll
    for (int k = 0; k < 64; k += 4) {
        float w0 = Wdt[(k + 0) * D_INNER + d];
        float w1 = Wdt[(k + 1) * D_INNER + d];
        float w2 = Wdt[(k + 2) * D_INNER + d];
        float w3 = Wdt[(k + 3) * D_INNER + d];
        #pragma unroll
        for (int i = 0; i < 16; ++i) {
            float4 v = *reinterpret_cast<const float4*>(&ds_[i][k]);
            acc[i] += v.x * w0 + v.y * w1 + v.z * w2 + v.w * w3;
        }
    }
    float b = bdt[d];
    #pragma unroll
    for (int i = 0; i < 16; ++i) {
        float v = acc[i] + b;
        float sp = fmaxf(v, 0.f) + log1pf(__expf(-fabsf(v)));
        dtout[(size_t)(m0 + i) * (2 * D_INNER) + d] = sp;
    }
}

// ---------------------------------------------------------------------------
// Selective scan + gating.  x_in read as bf16 hi/lo; y written as bf16 hi/lo.
// ---------------------------------------------------------------------------
#define SCHUNK 32

__global__ __launch_bounds__(256) void scan_k(
    const float* __restrict__ xzbuf,   // dt at col d, z at col 2048+d
    const ushort_t* __restrict__ xinh, const ushort_t* __restrict__ xinl,
    const float* __restrict__ dbc,
    const float* __restrict__ A_log, const float* __restrict__ Dv,
    ushort_t* __restrict__ Yh, ushort_t* __restrict__ Yl)
{
    __shared__ float xs[SCHUNK][16], dts[SCHUNK][16], Bs[SCHUNK][16], Cs[SCHUNK][16];
    __shared__ float ps[SCHUNK][16 * 17];   // [t][n*17+ch]
    const int tid = threadIdx.x;
    const int b = blockIdx.x >> 7;
    const int c0 = (blockIdx.x & 127) << 4;
    const int n = tid & 15, ch = tid >> 4;
    const int d = c0 + ch;
    const float Adn = -__expf(A_log[d * D_STATE + n]);
    const float Dn = Dv[c0 + n];
    float state = 0.f;
    const size_t base = (size_t)b * LSEQ;

    float xg[2], dtg[2], Bg[2], Cg[2], zg[2];
    #pragma unroll
    for (int jj = 0; jj < 2; ++jj) {
        size_t m = base + (ch + 16 * jj);
        size_t ox = m * D_INNER + c0 + n;
        xg[jj]  = bf2f(xinh[ox]) + bf2f(xinl[ox]);
        dtg[jj] = xzbuf[m * (2 * D_INNER) + c0 + n];
        Bg[jj]  = dbc[m * DBC_STRIDE + 64 + n];
        Cg[jj]  = dbc[m * DBC_STRIDE + 80 + n];
    }

    for (int t0 = 0; t0 < LSEQ; t0 += SCHUNK) {
        #pragma unroll
        for (int jj = 0; jj < 2; ++jj) {
            int r = ch + 16 * jj;
            xs[r][n] = xg[jj]; dts[r][n] = dtg[jj];
            Bs[r][n] = Bg[jj]; Cs[r][n] = Cg[jj];
        }
        __syncthreads();

        int t1 = (t0 + SCHUNK < LSEQ) ? t0 + SCHUNK : t0;
        #pragma unroll
        for (int jj = 0; jj < 2; ++jj) {
            size_t mn = base + t1 + (ch + 16 * jj);
            size_t mz = base + t0 + (ch + 16 * jj);
            size_t ox = mn * D_INNER + c0 + n;
            xg[jj]  = bf2f(xinh[ox]) + bf2f(xinl[ox]);
            dtg[jj] = xzbuf[mn * (2 * D_INNER) + c0 + n];
            Bg[jj]  = dbc[mn * DBC_STRIDE + 64 + n];
            Cg[jj]  = dbc[mn * DBC_STRIDE + 80 + n];
            zg[jj]  = xzbuf[mz * (2 * D_INNER) + D_INNER + c0 + n];
        }

        #pragma unroll
        for (int t = 0; t < SCHUNK; ++t) {
            float dtv = dts[t][ch];
            float xv  = xs[t][ch];
            float Bv  = Bs[t][n];
            float Cv  = Cs[t][n];
            float arg = fminf(fmaxf(dtv * Adn, -10.f), 10.f);
            float dA  = __expf(arg);
            float s   = state * dA + dtv * xv * Bv;
            state     = fminf(fmaxf(s, -10.f), 10.f);
            ps[t][n * 17 + ch] = state * Cv;
        }
        __syncthreads();

        #pragma unroll
        for (int jj = 0; jj < 2; ++jj) {
            int r = ch + 16 * jj;
            size_t m = base + t0 + r;
            float sum = 0.f;
            #pragma unroll
            for (int k = 0; k < 16; ++k)
                sum += ps[r][k * 17 + n];
            float yv = sum + Dn * xs[r][n];
            float z  = zg[jj];
            float sz = z / (1.f + __expf(-z));
            float val = yv * sz;
            ushort_t h = f2bf_rne(val);
            ushort_t l = f2bf_rne(val - bf2f(h));
            Yh[m * D_INNER + c0 + n] = h;
            Yl[m * D_INNER + c0 + n] = l;
        }
        __syncthreads();
    }
}

// ---------------------------------------------------------------------------
extern "C" void kernel_launch(void* const* d_in, const int* in_sizes, int n_in,
                              void* d_out, int out_size, void* d_ws, size_t ws_size,
                              hipStream_t stream)
{
    const float* x       = (const float*)d_in[0];
    const float* W_in    = (const float*)d_in[1];
    const float* W_conv  = (const float*)d_in[2];
    const float* b_conv  = (const float*)d_in[3];
    const float* W_xproj = (const float*)d_in[4];
    const float* W_dt    = (const float*)d_in[5];
    const float* b_dt    = (const float*)d_in[6];
    const float* A_log   = (const float*)d_in[7];
    const float* Dv      = (const float*)d_in[8];
    const float* W_out   = (const float*)d_in[9];
    float* out = (float*)d_out;

    // fp32 region
    float* xz  = (float*)d_ws;                              // 16.78M f
    float* dbc = xz + (size_t)M_TOT * 2 * D_INNER;          // 4096*128 f
    // bf16 region
    ushort_t* xh     = (ushort_t*)(dbc + (size_t)M_TOT * DBC_STRIDE);
    ushort_t* xl     = xh + (size_t)M_TOT * D_MODEL;
    ushort_t* WinTh  = xl + (size_t)M_TOT * D_MODEL;          // [4096][1024]
    ushort_t* WinTl  = WinTh + (size_t)2 * D_INNER * D_MODEL;
    ushort_t* WoutTh = WinTl + (size_t)2 * D_INNER * D_MODEL; // [1024][2048]
    ushort_t* WoutTl = WoutTh + (size_t)D_MODEL * D_INNER;
    ushort_t* WxTh   = WoutTl + (size_t)D_MODEL * D_INNER;    // [128][2048]
    ushort_t* WxTl   = WxTh + (size_t)DBC_STRIDE * D_INNER;
    ushort_t* xinh   = WxTl + (size_t)DBC_STRIDE * D_INNER;   // [4096][2048]
    ushort_t* xinl   = xinh + (size_t)M_TOT * D_INNER;
    ushort_t* yh     = xinl + (size_t)M_TOT * D_INNER;        // [4096][2048]
    ushort_t* yl     = yh + (size_t)M_TOT * D_INNER;

    // precompute: casts + weight transposes
    cast_hl_k<<<(M_TOT * D_MODEL) / 1024, 256, 0, stream>>>(x, xh, xl);
    transpose_cast_k<<<dim3((2 * D_INNER) / 32, D_MODEL / 32), 256, 0, stream>>>(
        W_in, WinTh, WinTl, D_MODEL, 2 * D_INNER);
    transpose_cast_k<<<dim3(D_MODEL / 32, D_INNER / 32), 256, 0, stream>>>(
        W_out, WoutTh, WoutTl, D_INNER, D_MODEL);
    transpose_cast_pad_k<<<dim3(DBC_STRIDE / 32, D_INNER / 32), 256, 0, stream>>>(
        W_xproj, WxTh, WxTl, D_INNER, DT_RANK + 2 * D_STATE);

    // 1) xz = x @ W_in          (M=4096, N=4096, K=1024)
    gemm_bf16s<<<dim3(32, 32), 256, 0, stream>>>(xh, xl, WinTh, WinTl, xz,
                                                 M_TOT, 2 * D_INNER, D_MODEL);
    // 2) conv + silu -> x_in bf16 hi/lo
    conv_silu_k<<<(M_TOT * D_INNER) / 256, 256, 0, stream>>>(xz, W_conv, b_conv, xinh, xinl);
    // 3) dbc = x_in @ W_xproj   (M=4096, N=128 padded, K=2048) via MFMA
    gemm_bf16s<<<dim3(1, 32), 256, 0, stream>>>(xinh, xinl, WxTh, WxTl, dbc,
                                                M_TOT, DBC_STRIDE, D_INNER);
    // 4) dt -> xz x-half (strided)
    dtproj_k<<<dim3(D_INNER / 256, M_TOT / 16), 256, 0, stream>>>(dbc, W_dt, b_dt, xz);
    // 5) scan + gate -> yh/yl bf16
    scan_k<<<NBATCH * (D_INNER / 16), 256, 0, stream>>>(xz, xinh, xinl, dbc, A_log, Dv, yh, yl);
    // 6) out = y @ W_out        (M=4096, N=1024, K=2048)
    gemm_bf16s<<<dim3(8, 32), 256, 0, stream>>>(yh, yl, WoutTh, WoutTl, out,
                                                M_TOT, D_MODEL, D_INNER);
}

// Round 5
// 615.857 us; speedup vs baseline: 2.4418x; 1.0682x over previous
//
#include <hip/hip_runtime.h>
#include <math.h>

#define D_MODEL 1024
#define D_INNER 2048
#define D_STATE 16
#define DT_RANK 64
#define LSEQ 2048
#define NBATCH 2
#define M_TOT (NBATCH * LSEQ)   // 4096 rows total
#define DBC_STRIDE 128          // padded xproj output stride

typedef unsigned short ushort_t;
typedef unsigned int uint_t;
typedef __attribute__((ext_vector_type(8))) short bf16x8;
typedef __attribute__((ext_vector_type(4))) float f32x4;

__device__ __forceinline__ ushort_t f2bf_rne(float f) {
    uint_t u = __float_as_uint(f);
    u += 0x7fffu + ((u >> 16) & 1u);
    return (ushort_t)(u >> 16);
}
__device__ __forceinline__ float bf2f(ushort_t h) {
    return __uint_as_float(((uint_t)h) << 16);
}

// ---------------------------------------------------------------------------
// Split-bf16 MFMA GEMM (3-term AhBh + AlBh + AhBl), BT[N][K] pre-transposed.
// 128x128 tile, 4 waves, BK=32, global_load_lds width=16, LDS chunk swizzle.
// BCOUT: additionally write C columns [64,96) transposed to BCTout[col-64][M]
// (used by the xproj call to produce B/C time-major for the scan).
// ---------------------------------------------------------------------------
template <bool BCOUT>
__global__ __launch_bounds__(256) void gemm_bf16s(
    const ushort_t* __restrict__ Ah, const ushort_t* __restrict__ Al,
    const ushort_t* __restrict__ BTh, const ushort_t* __restrict__ BTl,
    float* __restrict__ C, float* __restrict__ BCTout, int M, int N, int K)
{
    __shared__ __align__(16) ushort_t smem[4 * 128 * 32];   // Ah|Al|Bh|Bl tiles
    ushort_t* sA[2] = { smem,            smem + 4096 };
    ushort_t* sB[2] = { smem + 8192,     smem + 12288 };
    const int tid = threadIdx.x;
    const int lane = tid & 63;
    const int m0 = blockIdx.y * 128, n0 = blockIdx.x * 128;
    const int wave = tid >> 6;
    const int mw = (wave & 1) * 64, nw = (wave >> 1) * 64;
    const int fm = lane & 15, fk = lane >> 4;
    const int swz = fk ^ ((fm >> 1) & 3);

    f32x4 acc[4][4] = {};

    const int r_st0 = tid >> 2, cp0 = tid & 3;
    const int r_st1 = (256 + tid) >> 2, cp1 = tid & 3;
    const int cl0 = cp0 ^ ((r_st0 >> 1) & 3);
    const int cl1 = cp1 ^ ((r_st1 >> 1) & 3);
    const int ldsb0 = (tid & ~63) * 16;
    const int ldsb1 = (256 + (tid & ~63)) * 16;

    for (int k0 = 0; k0 < K; k0 += 32) {
        __syncthreads();
        {
            size_t ga0 = (size_t)(m0 + r_st0) * K + k0 + cl0 * 8;
            size_t ga1 = (size_t)(m0 + r_st1) * K + k0 + cl1 * 8;
            size_t gb0 = (size_t)(n0 + r_st0) * K + k0 + cl0 * 8;
            size_t gb1 = (size_t)(n0 + r_st1) * K + k0 + cl1 * 8;
            __builtin_amdgcn_global_load_lds(
                (const __attribute__((address_space(1))) void*)(Ah + ga0),
                (__attribute__((address_space(3))) void*)((char*)sA[0] + ldsb0), 16, 0, 0);
            __builtin_amdgcn_global_load_lds(
                (const __attribute__((address_space(1))) void*)(Ah + ga1),
                (__attribute__((address_space(3))) void*)((char*)sA[0] + ldsb1), 16, 0, 0);
            __builtin_amdgcn_global_load_lds(
                (const __attribute__((address_space(1))) void*)(Al + ga0),
                (__attribute__((address_space(3))) void*)((char*)sA[1] + ldsb0), 16, 0, 0);
            __builtin_amdgcn_global_load_lds(
                (const __attribute__((address_space(1))) void*)(Al + ga1),
                (__attribute__((address_space(3))) void*)((char*)sA[1] + ldsb1), 16, 0, 0);
            __builtin_amdgcn_global_load_lds(
                (const __attribute__((address_space(1))) void*)(BTh + gb0),
                (__attribute__((address_space(3))) void*)((char*)sB[0] + ldsb0), 16, 0, 0);
            __builtin_amdgcn_global_load_lds(
                (const __attribute__((address_space(1))) void*)(BTh + gb1),
                (__attribute__((address_space(3))) void*)((char*)sB[0] + ldsb1), 16, 0, 0);
            __builtin_amdgcn_global_load_lds(
                (const __attribute__((address_space(1))) void*)(BTl + gb0),
                (__attribute__((address_space(3))) void*)((char*)sB[1] + ldsb0), 16, 0, 0);
            __builtin_amdgcn_global_load_lds(
                (const __attribute__((address_space(1))) void*)(BTl + gb1),
                (__attribute__((address_space(3))) void*)((char*)sB[1] + ldsb1), 16, 0, 0);
        }
        __syncthreads();

        bf16x8 fAh[4], fAl[4], fBh[4], fBl[4];
        #pragma unroll
        for (int t = 0; t < 4; ++t) {
            int ra = (mw + t * 16 + fm) * 32 + swz * 8;
            int rb = (nw + t * 16 + fm) * 32 + swz * 8;
            fAh[t] = *reinterpret_cast<const bf16x8*>(&sA[0][ra]);
            fAl[t] = *reinterpret_cast<const bf16x8*>(&sA[1][ra]);
            fBh[t] = *reinterpret_cast<const bf16x8*>(&sB[0][rb]);
            fBl[t] = *reinterpret_cast<const bf16x8*>(&sB[1][rb]);
        }
        #pragma unroll
        for (int i = 0; i < 4; ++i)
            #pragma unroll
            for (int j = 0; j < 4; ++j) {
                acc[i][j] = __builtin_amdgcn_mfma_f32_16x16x32_bf16(fAh[i], fBh[j], acc[i][j], 0, 0, 0);
                acc[i][j] = __builtin_amdgcn_mfma_f32_16x16x32_bf16(fAl[i], fBh[j], acc[i][j], 0, 0, 0);
                acc[i][j] = __builtin_amdgcn_mfma_f32_16x16x32_bf16(fAh[i], fBl[j], acc[i][j], 0, 0, 0);
            }
    }

    #pragma unroll
    for (int i = 0; i < 4; ++i) {
        int row0 = m0 + mw + i * 16 + fk * 4;
        #pragma unroll
        for (int j = 0; j < 4; ++j) {
            int col = n0 + nw + j * 16 + fm;
            #pragma unroll
            for (int r = 0; r < 4; ++r)
                C[(size_t)(row0 + r) * N + col] = acc[i][j][r];
            if (BCOUT) {
                int cbase = n0 + nw + j * 16;
                if (cbase >= 64 && cbase < 96) {
                    float4 v = make_float4(acc[i][j][0], acc[i][j][1],
                                           acc[i][j][2], acc[i][j][3]);
                    *reinterpret_cast<float4*>(
                        &BCTout[(size_t)(col - 64) * M + row0]) = v;
                }
            }
        }
    }
}

// ---------------------------------------------------------------------------
// x -> (xh, xl) bf16 split, elementwise.
// ---------------------------------------------------------------------------
__global__ __launch_bounds__(256) void cast_hl_k(
    const float* __restrict__ X, ushort_t* __restrict__ Xh, ushort_t* __restrict__ Xl)
{
    int i4 = (blockIdx.x * 256 + threadIdx.x) * 4;
    float4 v = *reinterpret_cast<const float4*>(X + i4);
    ushort_t h[4], l[4];
    float vv[4] = { v.x, v.y, v.z, v.w };
    #pragma unroll
    for (int k = 0; k < 4; ++k) {
        h[k] = f2bf_rne(vv[k]);
        l[k] = f2bf_rne(vv[k] - bf2f(h[k]));
    }
    *reinterpret_cast<ushort2*>(Xh + i4)     = make_ushort2(h[0], h[1]);
    *reinterpret_cast<ushort2*>(Xh + i4 + 2) = make_ushort2(h[2], h[3]);
    *reinterpret_cast<ushort2*>(Xl + i4)     = make_ushort2(l[0], l[1]);
    *reinterpret_cast<ushort2*>(Xl + i4 + 2) = make_ushort2(l[2], l[3]);
}

// ---------------------------------------------------------------------------
// W[K][N] fp32 -> WT[N][K] bf16 hi/lo (tiled transpose, exact dims).
// ---------------------------------------------------------------------------
__global__ __launch_bounds__(256) void transpose_cast_k(
    const float* __restrict__ W, ushort_t* __restrict__ Th, ushort_t* __restrict__ Tl,
    int K, int N)
{
    __shared__ float tile[32][33];
    int n0 = blockIdx.x * 32, k0 = blockIdx.y * 32;
    int tx = threadIdx.x & 31, ty = threadIdx.x >> 5;
    #pragma unroll
    for (int i = 0; i < 32; i += 8)
        tile[ty + i][tx] = W[(size_t)(k0 + ty + i) * N + n0 + tx];
    __syncthreads();
    #pragma unroll
    for (int i = 0; i < 32; i += 8) {
        float v = tile[tx][ty + i];
        ushort_t h = f2bf_rne(v);
        ushort_t l = f2bf_rne(v - bf2f(h));
        size_t o = (size_t)(n0 + ty + i) * K + k0 + tx;
        Th[o] = h; Tl[o] = l;
    }
}

// ---------------------------------------------------------------------------
// W[K][N] fp32 -> WT[Npad][K] bf16 hi/lo, zero-padded rows N..Npad.
// ---------------------------------------------------------------------------
__global__ __launch_bounds__(256) void transpose_cast_pad_k(
    const float* __restrict__ W, ushort_t* __restrict__ Th, ushort_t* __restrict__ Tl,
    int K, int N)
{
    __shared__ float tile[32][33];
    int n0 = blockIdx.x * 32, k0 = blockIdx.y * 32;
    int tx = threadIdx.x & 31, ty = threadIdx.x >> 5;
    #pragma unroll
    for (int i = 0; i < 32; i += 8)
        tile[ty + i][tx] = (n0 + tx < N) ? W[(size_t)(k0 + ty + i) * N + n0 + tx] : 0.f;
    __syncthreads();
    #pragma unroll
    for (int i = 0; i < 32; i += 8) {
        float v = tile[tx][ty + i];
        ushort_t h = f2bf_rne(v);
        ushort_t l = f2bf_rne(v - bf2f(h));
        size_t o = (size_t)(n0 + ty + i) * K + k0 + tx;
        Th[o] = h; Tl[o] = l;
    }
}

// ---------------------------------------------------------------------------
// Depthwise causal conv + bias + SiLU, tiled.  Outputs:
//   xinh/xinl [m][d] bf16 (A operand of xproj GEMM)
//   xT        [d][m] fp32 (time-major, for the scan)
// Tile: 64 m x 64 c. 256 threads; thread = (c_l, mg), computes 16 m values.
// ---------------------------------------------------------------------------
__global__ __launch_bounds__(256) void conv_silu_k(
    const float* __restrict__ xz, const float* __restrict__ Wc,
    const float* __restrict__ bc, ushort_t* __restrict__ xinh,
    ushort_t* __restrict__ xinl, float* __restrict__ xT)
{
    __shared__ float tile[67][64];
    const int c0 = blockIdx.x * 64;
    const int m0 = blockIdx.y * 64;
    const int bstart = m0 & ~(LSEQ - 1);     // batch start row (causal pad)
    const int tid = threadIdx.x;

    for (int e = tid; e < 67 * 64; e += 256) {
        int r = e >> 6, c = e & 63;
        int g = m0 - 3 + r;
        tile[r][c] = (g >= bstart) ? xz[(size_t)g * (2 * D_INNER) + c0 + c] : 0.f;
    }
    __syncthreads();

    const int c_l = tid & 63, mg = tid >> 6;
    const int c = c0 + c_l;
    const float w0 = Wc[c], w1 = Wc[D_INNER + c];
    const float w2 = Wc[2 * D_INNER + c], w3 = Wc[3 * D_INNER + c];
    const float bb = bc[c];
    float xtbuf[16];
    #pragma unroll
    for (int mi = 0; mi < 16; ++mi) {
        int r = mg * 16 + mi;
        float acc = bb + tile[r][c_l] * w0 + tile[r + 1][c_l] * w1
                       + tile[r + 2][c_l] * w2 + tile[r + 3][c_l] * w3;
        float sv = acc / (1.f + __expf(-acc));
        ushort_t h = f2bf_rne(sv);
        ushort_t lo = f2bf_rne(sv - bf2f(h));
        size_t m = (size_t)(m0 + r);
        xinh[m * D_INNER + c] = h;
        xinl[m * D_INNER + c] = lo;
        xtbuf[mi] = sv;
    }
    float* xtp = xT + (size_t)c * M_TOT + m0 + mg * 16;
    #pragma unroll
    for (int q = 0; q < 4; ++q)
        *reinterpret_cast<float4*>(xtp + 4 * q) =
            make_float4(xtbuf[4 * q], xtbuf[4 * q + 1], xtbuf[4 * q + 2], xtbuf[4 * q + 3]);
}

// ---------------------------------------------------------------------------
// dt = softplus(dbc[:, :64] @ W_dt + b_dt) -> dtT[d][m] time-major fp32.
// ---------------------------------------------------------------------------
__global__ __launch_bounds__(256) void dtproj_k(
    const float* __restrict__ dbc, const float* __restrict__ Wdt,
    const float* __restrict__ bdt, float* __restrict__ dtT)
{
    __shared__ float ds_[16][64];
    int tid = threadIdx.x;
    int d = blockIdx.x * 256 + tid;
    int m0 = blockIdx.y * 16;
    #pragma unroll
    for (int jj = 0; jj < 4; ++jj) {
        int e = tid + 256 * jj; int r = e >> 6, c = e & 63;
        ds_[r][c] = dbc[(size_t)(m0 + r) * DBC_STRIDE + c];
    }
    __syncthreads();
    float acc[16] = {};
    #pragma unroll
    for (int k = 0; k < 64; k += 4) {
        float w0 = Wdt[(k + 0) * D_INNER + d];
        float w1 = Wdt[(k + 1) * D_INNER + d];
        float w2 = Wdt[(k + 2) * D_INNER + d];
        float w3 = Wdt[(k + 3) * D_INNER + d];
        #pragma unroll
        for (int i = 0; i < 16; ++i) {
            float4 v = *reinterpret_cast<const float4*>(&ds_[i][k]);
            acc[i] += v.x * w0 + v.y * w1 + v.z * w2 + v.w * w3;
        }
    }
    float b = bdt[d];
    float sp[16];
    #pragma unroll
    for (int i = 0; i < 16; ++i) {
        float v = acc[i] + b;
        sp[i] = fmaxf(v, 0.f) + log1pf(__expf(-fabsf(v)));
    }
    float* dp = dtT + (size_t)d * M_TOT + m0;
    #pragma unroll
    for (int q = 0; q < 4; ++q)
        *reinterpret_cast<float4*>(dp + 4 * q) =
            make_float4(sp[4 * q], sp[4 * q + 1], sp[4 * q + 2], sp[4 * q + 3]);
}

// ---------------------------------------------------------------------------
// Selective scan v3: register-resident, barrier-free.
// Inputs time-major: dtT[d][m], xT[d][m], BCT[n][m] (rows 0..15 B, 16..31 C).
// Block = 4 waves, wave w owns channels c0+4w..c0+4w+3; lane=(cl, n).
// Per step: state = clamp(fma(state, dA, dt*x*B)); p = state*C (+D*x at n==0)
// -> ds_write to wave-private pad. Every 16 steps: same-wave reduction over n
// (in-order LDS pipe, wave_barrier only), gate with silu(z), bf16-split store.
// Inputs double-buffered in registers (launch_bounds(256,1) -> full VGPR file).
// ---------------------------------------------------------------------------
__global__ __launch_bounds__(256, 1) void scan_k(
    const float* __restrict__ dtT, const float* __restrict__ xT,
    const float* __restrict__ BCT, const float* __restrict__ xz,
    const float* __restrict__ A_log, const float* __restrict__ Dv,
    ushort_t* __restrict__ Yh, ushort_t* __restrict__ Yl)
{
    __shared__ float ps[4][16][68];     // [wave][t][n*4+cl]  (17.4 KB)
    const int tid = threadIdx.x;
    const int w = tid >> 6, lane = tid & 63;
    const int n = lane & 15, cl = lane >> 4;      // phase-B lane = (channel, state)
    const int t_r = lane >> 2, cl_r = lane & 3;   // phase-C lane = (time, channel)
    const int b = blockIdx.x >> 7;
    const int c0 = (blockIdx.x & 127) << 4;
    const int d = c0 + w * 4 + cl;
    const int d_out = c0 + w * 4 + cl_r;
    const int n4cl = n * 4 + cl;
    const size_t base = (size_t)b * LSEQ;

    const float Adn = -__expf(A_log[d * D_STATE + n]);
    const float DdEff = (n == 0) ? Dv[d] : 0.f;
    float state = 0.f;

    const float* dtp = dtT + (size_t)d * M_TOT + base;
    const float* xp  = xT  + (size_t)d * M_TOT + base;
    const float* Bp  = BCT + (size_t)n * M_TOT + base;
    const float* Cp  = BCT + (size_t)(16 + n) * M_TOT + base;

#define ZLOAD(T0) xz[(size_t)(base + (T0) + t_r) * (2 * D_INNER) + D_INNER + d_out]

#define LOAD_CHUNK(DT, X, BB, CC, TL)                                        \
    {                                                                         \
        int tt = ((TL) < LSEQ) ? (TL) : (TL) - 16;                            \
        _Pragma("unroll")                                                     \
        for (int q = 0; q < 4; ++q) {                                         \
            *reinterpret_cast<float4*>(&DT[4 * q]) = *reinterpret_cast<const float4*>(dtp + tt + 4 * q); \
            *reinterpret_cast<float4*>(&X [4 * q]) = *reinterpret_cast<const float4*>(xp  + tt + 4 * q); \
            *reinterpret_cast<float4*>(&BB[4 * q]) = *reinterpret_cast<const float4*>(Bp  + tt + 4 * q); \
            *reinterpret_cast<float4*>(&CC[4 * q]) = *reinterpret_cast<const float4*>(Cp  + tt + 4 * q); \
        }                                                                     \
    }

#define DO_CHUNK(DT, X, BB, CC, ZV, T0)                                       \
    {                                                                         \
        _Pragma("unroll")                                                     \
        for (int t = 0; t < 16; ++t) {                                        \
            float dtv = DT[t], xv = X[t];                                     \
            float arg = fminf(fmaxf(dtv * Adn, -10.f), 10.f);                 \
            float dA = __expf(arg);                                           \
            float s = state * dA + dtv * xv * BB[t];                          \
            state = fminf(fmaxf(s, -10.f), 10.f);                             \
            ps[w][t][n4cl] = state * CC[t] + DdEff * xv;                      \
        }                                                                     \
        __builtin_amdgcn_wave_barrier();                                      \
        float sum = 0.f;                                                      \
        _Pragma("unroll")                                                     \
        for (int k = 0; k < 16; ++k) sum += ps[w][t_r][k * 4 + cl_r];         \
        float zz = (ZV);                                                      \
        float sz = zz / (1.f + __expf(-zz));                                  \
        float val = sum * sz;                                                 \
        ushort_t hh = f2bf_rne(val);                                          \
        ushort_t ll = f2bf_rne(val - bf2f(hh));                               \
        size_t om = (size_t)(base + (T0) + t_r) * D_INNER + d_out;            \
        Yh[om] = hh; Yl[om] = ll;                                             \
        __builtin_amdgcn_wave_barrier();                                      \
    }

    float dtA[16], xA[16], BA[16], CA[16];
    float dtB[16], xB[16], BB_[16], CB[16];
    float zA, zB;

    LOAD_CHUNK(dtA, xA, BA, CA, 0);
    zA = ZLOAD(0);

    for (int t0 = 0; t0 < LSEQ; t0 += 32) {
        LOAD_CHUNK(dtB, xB, BB_, CB, t0 + 16);
        zB = ZLOAD(t0 + 16);
        DO_CHUNK(dtA, xA, BA, CA, zA, t0);
        int t2 = (t0 + 32 < LSEQ) ? t0 + 32 : 0;
        LOAD_CHUNK(dtA, xA, BA, CA, t2);
        zA = ZLOAD(t2);
        DO_CHUNK(dtB, xB, BB_, CB, zB, t0 + 16);
    }
#undef ZLOAD
#undef LOAD_CHUNK
#undef DO_CHUNK
}

// ---------------------------------------------------------------------------
extern "C" void kernel_launch(void* const* d_in, const int* in_sizes, int n_in,
                              void* d_out, int out_size, void* d_ws, size_t ws_size,
                              hipStream_t stream)
{
    const float* x       = (const float*)d_in[0];
    const float* W_in    = (const float*)d_in[1];
    const float* W_conv  = (const float*)d_in[2];
    const float* b_conv  = (const float*)d_in[3];
    const float* W_xproj = (const float*)d_in[4];
    const float* W_dt    = (const float*)d_in[5];
    const float* b_dt    = (const float*)d_in[6];
    const float* A_log   = (const float*)d_in[7];
    const float* Dv      = (const float*)d_in[8];
    const float* W_out   = (const float*)d_in[9];
    float* out = (float*)d_out;

    // fp32 region
    float* xz  = (float*)d_ws;                               // 16.78M f
    float* dbc = xz + (size_t)M_TOT * 2 * D_INNER;           // 4096*128 f
    float* BCT = dbc + (size_t)M_TOT * DBC_STRIDE;           // 32*4096 f
    // bf16 region
    ushort_t* xh     = (ushort_t*)(BCT + (size_t)32 * M_TOT);
    ushort_t* xl     = xh + (size_t)M_TOT * D_MODEL;
    ushort_t* WinTh  = xl + (size_t)M_TOT * D_MODEL;          // [4096][1024]
    ushort_t* WinTl  = WinTh + (size_t)2 * D_INNER * D_MODEL;
    ushort_t* WoutTh = WinTl + (size_t)2 * D_INNER * D_MODEL; // [1024][2048]
    ushort_t* WoutTl = WoutTh + (size_t)D_MODEL * D_INNER;
    ushort_t* WxTh   = WoutTl + (size_t)D_MODEL * D_INNER;    // [128][2048]
    ushort_t* WxTl   = WxTh + (size_t)DBC_STRIDE * D_INNER;
    ushort_t* xinh   = WxTl + (size_t)DBC_STRIDE * D_INNER;   // [4096][2048]
    ushort_t* xinl   = xinh + (size_t)M_TOT * D_INNER;
    ushort_t* yh     = xinl + (size_t)M_TOT * D_INNER;        // [4096][2048]
    ushort_t* yl     = yh + (size_t)M_TOT * D_INNER;
    // aliases (stream-ordered reuse of dead regions):
    float* xT  = (float*)xh;     // [2048][4096] fp32 over xh|xl|WinTh|WinTl (dead after gemm#1)
    float* dtT = (float*)xinh;   // [2048][4096] fp32 over xinh|xinl (dead after xproj gemm)

    // precompute: casts + weight transposes
    cast_hl_k<<<(M_TOT * D_MODEL) / 1024, 256, 0, stream>>>(x, xh, xl);
    transpose_cast_k<<<dim3((2 * D_INNER) / 32, D_MODEL / 32), 256, 0, stream>>>(
        W_in, WinTh, WinTl, D_MODEL, 2 * D_INNER);
    transpose_cast_k<<<dim3(D_MODEL / 32, D_INNER / 32), 256, 0, stream>>>(
        W_out, WoutTh, WoutTl, D_INNER, D_MODEL);
    transpose_cast_pad_k<<<dim3(DBC_STRIDE / 32, D_INNER / 32), 256, 0, stream>>>(
        W_xproj, WxTh, WxTl, D_INNER, DT_RANK + 2 * D_STATE);

    // 1) xz = x @ W_in          (M=4096, N=4096, K=1024)
    gemm_bf16s<false><<<dim3(32, 32), 256, 0, stream>>>(
        xh, xl, WinTh, WinTl, xz, nullptr, M_TOT, 2 * D_INNER, D_MODEL);
    // 2) conv + silu -> xinh/xinl [m][d] + xT [d][m]   (overwrites xh/xl/WinT)
    conv_silu_k<<<dim3(D_INNER / 64, M_TOT / 64), 256, 0, stream>>>(
        xz, W_conv, b_conv, xinh, xinl, xT);
    // 3) dbc = x_in @ W_xproj   (N=128 padded) + BCT time-major B/C
    gemm_bf16s<true><<<dim3(1, 32), 256, 0, stream>>>(
        xinh, xinl, WxTh, WxTl, dbc, BCT, M_TOT, DBC_STRIDE, D_INNER);
    // 4) dt -> dtT [d][m]       (overwrites xinh/xinl)
    dtproj_k<<<dim3(D_INNER / 256, M_TOT / 16), 256, 0, stream>>>(dbc, W_dt, b_dt, dtT);
    // 5) scan + gate -> yh/yl bf16
    scan_k<<<NBATCH * (D_INNER / 16), 256, 0, stream>>>(
        dtT, xT, BCT, xz, A_log, Dv, yh, yl);
    // 6) out = y @ W_out        (M=4096, N=1024, K=2048)
    gemm_bf16s<false><<<dim3(8, 32), 256, 0, stream>>>(
        yh, yl, WoutTh, WoutTl, out, nullptr, M_TOT, D_MODEL, D_INNER);
}

// Round 6
// 605.872 us; speedup vs baseline: 2.4820x; 1.0165x over previous
//
#include <hip/hip_runtime.h>
#include <math.h>

#define D_MODEL 1024
#define D_INNER 2048
#define D_STATE 16
#define DT_RANK 64
#define LSEQ 2048
#define NBATCH 2
#define M_TOT (NBATCH * LSEQ)   // 4096 rows total
#define DBC_STRIDE 128          // padded xproj output stride

typedef unsigned short ushort_t;
typedef unsigned int uint_t;
typedef __attribute__((ext_vector_type(8))) short bf16x8;
typedef __attribute__((ext_vector_type(4))) float f32x4;

__device__ __forceinline__ ushort_t f2bf_rne(float f) {
    uint_t u = __float_as_uint(f);
    u += 0x7fffu + ((u >> 16) & 1u);
    return (ushort_t)(u >> 16);
}
__device__ __forceinline__ float bf2f(ushort_t h) {
    return __uint_as_float(((uint_t)h) << 16);
}

// ---------------------------------------------------------------------------
// Split-bf16 MFMA GEMM (3-term AhBh + AlBh + AhBl), BT[N][K] pre-transposed.
// 128x128 tile, 4 waves, BK=32, global_load_lds width=16, LDS chunk swizzle.
// BCOUT: additionally write C columns [64,96) transposed to BCTout[col-64][M].
// ---------------------------------------------------------------------------
template <bool BCOUT>
__global__ __launch_bounds__(256) void gemm_bf16s(
    const ushort_t* __restrict__ Ah, const ushort_t* __restrict__ Al,
    const ushort_t* __restrict__ BTh, const ushort_t* __restrict__ BTl,
    float* __restrict__ C, float* __restrict__ BCTout, int M, int N, int K)
{
    __shared__ __align__(16) ushort_t smem[4 * 128 * 32];   // Ah|Al|Bh|Bl tiles
    ushort_t* sA[2] = { smem,            smem + 4096 };
    ushort_t* sB[2] = { smem + 8192,     smem + 12288 };
    const int tid = threadIdx.x;
    const int lane = tid & 63;
    const int m0 = blockIdx.y * 128, n0 = blockIdx.x * 128;
    const int wave = tid >> 6;
    const int mw = (wave & 1) * 64, nw = (wave >> 1) * 64;
    const int fm = lane & 15, fk = lane >> 4;
    const int swz = fk ^ ((fm >> 1) & 3);

    f32x4 acc[4][4] = {};

    const int r_st0 = tid >> 2, cp0 = tid & 3;
    const int r_st1 = (256 + tid) >> 2, cp1 = tid & 3;
    const int cl0 = cp0 ^ ((r_st0 >> 1) & 3);
    const int cl1 = cp1 ^ ((r_st1 >> 1) & 3);
    const int ldsb0 = (tid & ~63) * 16;
    const int ldsb1 = (256 + (tid & ~63)) * 16;

    for (int k0 = 0; k0 < K; k0 += 32) {
        __syncthreads();
        {
            size_t ga0 = (size_t)(m0 + r_st0) * K + k0 + cl0 * 8;
            size_t ga1 = (size_t)(m0 + r_st1) * K + k0 + cl1 * 8;
            size_t gb0 = (size_t)(n0 + r_st0) * K + k0 + cl0 * 8;
            size_t gb1 = (size_t)(n0 + r_st1) * K + k0 + cl1 * 8;
            __builtin_amdgcn_global_load_lds(
                (const __attribute__((address_space(1))) void*)(Ah + ga0),
                (__attribute__((address_space(3))) void*)((char*)sA[0] + ldsb0), 16, 0, 0);
            __builtin_amdgcn_global_load_lds(
                (const __attribute__((address_space(1))) void*)(Ah + ga1),
                (__attribute__((address_space(3))) void*)((char*)sA[0] + ldsb1), 16, 0, 0);
            __builtin_amdgcn_global_load_lds(
                (const __attribute__((address_space(1))) void*)(Al + ga0),
                (__attribute__((address_space(3))) void*)((char*)sA[1] + ldsb0), 16, 0, 0);
            __builtin_amdgcn_global_load_lds(
                (const __attribute__((address_space(1))) void*)(Al + ga1),
                (__attribute__((address_space(3))) void*)((char*)sA[1] + ldsb1), 16, 0, 0);
            __builtin_amdgcn_global_load_lds(
                (const __attribute__((address_space(1))) void*)(BTh + gb0),
                (__attribute__((address_space(3))) void*)((char*)sB[0] + ldsb0), 16, 0, 0);
            __builtin_amdgcn_global_load_lds(
                (const __attribute__((address_space(1))) void*)(BTh + gb1),
                (__attribute__((address_space(3))) void*)((char*)sB[0] + ldsb1), 16, 0, 0);
            __builtin_amdgcn_global_load_lds(
                (const __attribute__((address_space(1))) void*)(BTl + gb0),
                (__attribute__((address_space(3))) void*)((char*)sB[1] + ldsb0), 16, 0, 0);
            __builtin_amdgcn_global_load_lds(
                (const __attribute__((address_space(1))) void*)(BTl + gb1),
                (__attribute__((address_space(3))) void*)((char*)sB[1] + ldsb1), 16, 0, 0);
        }
        __syncthreads();

        bf16x8 fAh[4], fAl[4], fBh[4], fBl[4];
        #pragma unroll
        for (int t = 0; t < 4; ++t) {
            int ra = (mw + t * 16 + fm) * 32 + swz * 8;
            int rb = (nw + t * 16 + fm) * 32 + swz * 8;
            fAh[t] = *reinterpret_cast<const bf16x8*>(&sA[0][ra]);
            fAl[t] = *reinterpret_cast<const bf16x8*>(&sA[1][ra]);
            fBh[t] = *reinterpret_cast<const bf16x8*>(&sB[0][rb]);
            fBl[t] = *reinterpret_cast<const bf16x8*>(&sB[1][rb]);
        }
        #pragma unroll
        for (int i = 0; i < 4; ++i)
            #pragma unroll
            for (int j = 0; j < 4; ++j) {
                acc[i][j] = __builtin_amdgcn_mfma_f32_16x16x32_bf16(fAh[i], fBh[j], acc[i][j], 0, 0, 0);
                acc[i][j] = __builtin_amdgcn_mfma_f32_16x16x32_bf16(fAl[i], fBh[j], acc[i][j], 0, 0, 0);
                acc[i][j] = __builtin_amdgcn_mfma_f32_16x16x32_bf16(fAh[i], fBl[j], acc[i][j], 0, 0, 0);
            }
    }

    #pragma unroll
    for (int i = 0; i < 4; ++i) {
        int row0 = m0 + mw + i * 16 + fk * 4;
        #pragma unroll
        for (int j = 0; j < 4; ++j) {
            int col = n0 + nw + j * 16 + fm;
            #pragma unroll
            for (int r = 0; r < 4; ++r)
                C[(size_t)(row0 + r) * N + col] = acc[i][j][r];
            if (BCOUT) {
                int cbase = n0 + nw + j * 16;
                if (cbase >= 64 && cbase < 96) {
                    float4 v = make_float4(acc[i][j][0], acc[i][j][1],
                                           acc[i][j][2], acc[i][j][3]);
                    *reinterpret_cast<float4*>(
                        &BCTout[(size_t)(col - 64) * M + row0]) = v;
                }
            }
        }
    }
}

// ---------------------------------------------------------------------------
// x -> (xh, xl) bf16 split, elementwise.
// ---------------------------------------------------------------------------
__global__ __launch_bounds__(256) void cast_hl_k(
    const float* __restrict__ X, ushort_t* __restrict__ Xh, ushort_t* __restrict__ Xl)
{
    int i4 = (blockIdx.x * 256 + threadIdx.x) * 4;
    float4 v = *reinterpret_cast<const float4*>(X + i4);
    ushort_t h[4], l[4];
    float vv[4] = { v.x, v.y, v.z, v.w };
    #pragma unroll
    for (int k = 0; k < 4; ++k) {
        h[k] = f2bf_rne(vv[k]);
        l[k] = f2bf_rne(vv[k] - bf2f(h[k]));
    }
    *reinterpret_cast<ushort2*>(Xh + i4)     = make_ushort2(h[0], h[1]);
    *reinterpret_cast<ushort2*>(Xh + i4 + 2) = make_ushort2(h[2], h[3]);
    *reinterpret_cast<ushort2*>(Xl + i4)     = make_ushort2(l[0], l[1]);
    *reinterpret_cast<ushort2*>(Xl + i4 + 2) = make_ushort2(l[2], l[3]);
}

// ---------------------------------------------------------------------------
// W[K][N] fp32 -> WT[N][K] bf16 hi/lo (tiled transpose, exact dims).
// ---------------------------------------------------------------------------
__global__ __launch_bounds__(256) void transpose_cast_k(
    const float* __restrict__ W, ushort_t* __restrict__ Th, ushort_t* __restrict__ Tl,
    int K, int N)
{
    __shared__ float tile[32][33];
    int n0 = blockIdx.x * 32, k0 = blockIdx.y * 32;
    int tx = threadIdx.x & 31, ty = threadIdx.x >> 5;
    #pragma unroll
    for (int i = 0; i < 32; i += 8)
        tile[ty + i][tx] = W[(size_t)(k0 + ty + i) * N + n0 + tx];
    __syncthreads();
    #pragma unroll
    for (int i = 0; i < 32; i += 8) {
        float v = tile[tx][ty + i];
        ushort_t h = f2bf_rne(v);
        ushort_t l = f2bf_rne(v - bf2f(h));
        size_t o = (size_t)(n0 + ty + i) * K + k0 + tx;
        Th[o] = h; Tl[o] = l;
    }
}

// ---------------------------------------------------------------------------
// W[K][N] fp32 -> WT[Npad][K] bf16 hi/lo, zero-padded rows N..Npad.
// ---------------------------------------------------------------------------
__global__ __launch_bounds__(256) void transpose_cast_pad_k(
    const float* __restrict__ W, ushort_t* __restrict__ Th, ushort_t* __restrict__ Tl,
    int K, int N)
{
    __shared__ float tile[32][33];
    int n0 = blockIdx.x * 32, k0 = blockIdx.y * 32;
    int tx = threadIdx.x & 31, ty = threadIdx.x >> 5;
    #pragma unroll
    for (int i = 0; i < 32; i += 8)
        tile[ty + i][tx] = (n0 + tx < N) ? W[(size_t)(k0 + ty + i) * N + n0 + tx] : 0.f;
    __syncthreads();
    #pragma unroll
    for (int i = 0; i < 32; i += 8) {
        float v = tile[tx][ty + i];
        ushort_t h = f2bf_rne(v);
        ushort_t l = f2bf_rne(v - bf2f(h));
        size_t o = (size_t)(n0 + ty + i) * K + k0 + tx;
        Th[o] = h; Tl[o] = l;
    }
}

// ---------------------------------------------------------------------------
// Depthwise causal conv + bias + SiLU, tiled.  Outputs xinh/xinl [m][d] bf16
// and xT [d][m] fp32 (time-major for the scan).
// ---------------------------------------------------------------------------
__global__ __launch_bounds__(256) void conv_silu_k(
    const float* __restrict__ xz, const float* __restrict__ Wc,
    const float* __restrict__ bc, ushort_t* __restrict__ xinh,
    ushort_t* __restrict__ xinl, float* __restrict__ xT)
{
    __shared__ float tile[67][64];
    const int c0 = blockIdx.x * 64;
    const int m0 = blockIdx.y * 64;
    const int bstart = m0 & ~(LSEQ - 1);
    const int tid = threadIdx.x;

    for (int e = tid; e < 67 * 64; e += 256) {
        int r = e >> 6, c = e & 63;
        int g = m0 - 3 + r;
        tile[r][c] = (g >= bstart) ? xz[(size_t)g * (2 * D_INNER) + c0 + c] : 0.f;
    }
    __syncthreads();

    const int c_l = tid & 63, mg = tid >> 6;
    const int c = c0 + c_l;
    const float w0 = Wc[c], w1 = Wc[D_INNER + c];
    const float w2 = Wc[2 * D_INNER + c], w3 = Wc[3 * D_INNER + c];
    const float bb = bc[c];
    float xtbuf[16];
    #pragma unroll
    for (int mi = 0; mi < 16; ++mi) {
        int r = mg * 16 + mi;
        float acc = bb + tile[r][c_l] * w0 + tile[r + 1][c_l] * w1
                       + tile[r + 2][c_l] * w2 + tile[r + 3][c_l] * w3;
        float sv = acc / (1.f + __expf(-acc));
        ushort_t h = f2bf_rne(sv);
        ushort_t lo = f2bf_rne(sv - bf2f(h));
        size_t m = (size_t)(m0 + r);
        xinh[m * D_INNER + c] = h;
        xinl[m * D_INNER + c] = lo;
        xtbuf[mi] = sv;
    }
    float* xtp = xT + (size_t)c * M_TOT + m0 + mg * 16;
    #pragma unroll
    for (int q = 0; q < 4; ++q)
        *reinterpret_cast<float4*>(xtp + 4 * q) =
            make_float4(xtbuf[4 * q], xtbuf[4 * q + 1], xtbuf[4 * q + 2], xtbuf[4 * q + 3]);
}

// ---------------------------------------------------------------------------
// dt = softplus(dbc[:, :64] @ W_dt + b_dt) -> dtT[d][m] time-major fp32.
// ---------------------------------------------------------------------------
__global__ __launch_bounds__(256) void dtproj_k(
    const float* __restrict__ dbc, const float* __restrict__ Wdt,
    const float* __restrict__ bdt, float* __restrict__ dtT)
{
    __shared__ float ds_[16][64];
    int tid = threadIdx.x;
    int d = blockIdx.x * 256 + tid;
    int m0 = blockIdx.y * 16;
    #pragma unroll
    for (int jj = 0; jj < 4; ++jj) {
        int e = tid + 256 * jj; int r = e >> 6, c = e & 63;
        ds_[r][c] = dbc[(size_t)(m0 + r) * DBC_STRIDE + c];
    }
    __syncthreads();
    float acc[16] = {};
    #pragma unroll
    for (int k = 0; k < 64; k += 4) {
        float w0 = Wdt[(k + 0) * D_INNER + d];
        float w1 = Wdt[(k + 1) * D_INNER + d];
        float w2 = Wdt[(k + 2) * D_INNER + d];
        float w3 = Wdt[(k + 3) * D_INNER + d];
        #pragma unroll
        for (int i = 0; i < 16; ++i) {
            float4 v = *reinterpret_cast<const float4*>(&ds_[i][k]);
            acc[i] += v.x * w0 + v.y * w1 + v.z * w2 + v.w * w3;
        }
    }
    float b = bdt[d];
    float sp[16];
    #pragma unroll
    for (int i = 0; i < 16; ++i) {
        float v = acc[i] + b;
        sp[i] = fmaxf(v, 0.f) + log1pf(__expf(-fabsf(v)));
    }
    float* dp = dtT + (size_t)d * M_TOT + m0;
    #pragma unroll
    for (int q = 0; q < 4; ++q)
        *reinterpret_cast<float4*>(dp + 4 * q) =
            make_float4(sp[4 * q], sp[4 * q + 1], sp[4 * q + 2], sp[4 * q + 3]);
}

// ---------------------------------------------------------------------------
// Selective scan v4: 3-stage software pipeline; serial chain = fma + clamp.
// Per 16-step chunk: PREP (dA=exp(clamp(dt*A)), u=dt*x*B — off-chain),
// SERIAL (state=clamp(state*dA+u), st[] in regs) interleaved with PREP(next),
// POST (p=st*C+D*x -> LDS transpose, reduce over n, gate, bf16-split store).
// Loads prefetch distance 2 (4 raw slots, unroll 4).
// ---------------------------------------------------------------------------
__global__ __launch_bounds__(256, 1) void scan_k(
    const float* __restrict__ dtT, const float* __restrict__ xT,
    const float* __restrict__ BCT, const float* __restrict__ xz,
    const float* __restrict__ A_log, const float* __restrict__ Dv,
    ushort_t* __restrict__ Yh, ushort_t* __restrict__ Yl)
{
    __shared__ float ps[4][16][68];     // [wave][t][n*4+cl]
    const int tid = threadIdx.x;
    const int w = tid >> 6, lane = tid & 63;
    const int n = lane & 15, cl = lane >> 4;      // serial lane = (state, channel)
    const int i_w = n * 4 + cl;
    const int t_r = lane >> 2, cl_r = lane & 3;   // reduce lane = (time, channel)
    const int b = blockIdx.x >> 7;
    const int c0 = (blockIdx.x & 127) << 4;
    const int d = c0 + w * 4 + cl;
    const int d_out = c0 + w * 4 + cl_r;
    const size_t base = (size_t)b * LSEQ;

    const float Adn = -__expf(A_log[d * D_STATE + n]);
    const float DdEff = (n == 0) ? Dv[d] : 0.f;
    float state = 0.f;

    const float* dtp = dtT + (size_t)d * M_TOT + base;
    const float* xp  = xT  + (size_t)d * M_TOT + base;
    const float* Bp  = BCT + (size_t)n * M_TOT + base;
    const float* Cp  = BCT + (size_t)(16 + n) * M_TOT + base;

    float rdt[4][16], rx[4][16], rB[4][16], rC[4][16], rz[4];
    float pdA[2][16], pu[2][16];

#define LOADC(S, CH)                                                          \
    {                                                                         \
        int tt = (CH) * 16;                                                   \
        _Pragma("unroll")                                                     \
        for (int q = 0; q < 4; ++q) {                                         \
            *reinterpret_cast<float4*>(&rdt[S][4 * q]) = *reinterpret_cast<const float4*>(dtp + tt + 4 * q); \
            *reinterpret_cast<float4*>(&rx [S][4 * q]) = *reinterpret_cast<const float4*>(xp  + tt + 4 * q); \
            *reinterpret_cast<float4*>(&rB [S][4 * q]) = *reinterpret_cast<const float4*>(Bp  + tt + 4 * q); \
            *reinterpret_cast<float4*>(&rC [S][4 * q]) = *reinterpret_cast<const float4*>(Cp  + tt + 4 * q); \
        }                                                                     \
        rz[S] = xz[(base + tt + t_r) * (2 * D_INNER) + D_INNER + d_out];      \
    }

#define PREPC(P, S)                                                           \
    _Pragma("unroll")                                                         \
    for (int t = 0; t < 16; ++t) {                                            \
        float a = fminf(fmaxf(rdt[S][t] * Adn, -10.f), 10.f);                 \
        pdA[P][t] = __expf(a);                                                \
        pu[P][t]  = rdt[S][t] * rx[S][t] * rB[S][t];                          \
    }

    LOADC(0, 0);
    LOADC(1, 1);
    PREPC(0, 0);

    #pragma unroll 4
    for (int c = 0; c < 128; ++c) {
        const int S  = c & 3;           // chunk being consumed
        const int Sn = (c + 1) & 3;     // chunk being prepped
        const int Sl = (c + 2) & 3;     // chunk being loaded
        const int P  = c & 1, Pn = (c + 1) & 1;
        int cn = (c + 2 < 128) ? c + 2 : 0;
        LOADC(Sl, cn);

        // SERIAL(c) interleaved with PREP(c+1) — both register-only
        float st[16];
        #pragma unroll
        for (int t = 0; t < 16; ++t) {
            float s = state * pdA[P][t] + pu[P][t];
            state = fminf(fmaxf(s, -10.f), 10.f);
            st[t] = state;
            float a = fminf(fmaxf(rdt[Sn][t] * Adn, -10.f), 10.f);
            pdA[Pn][t] = __expf(a);
            pu[Pn][t]  = rdt[Sn][t] * rx[Sn][t] * rB[Sn][t];
        }

        // POST(c): p -> LDS transpose, reduce over n, gate, store
        #pragma unroll
        for (int t = 0; t < 16; ++t)
            ps[w][t][i_w] = st[t] * rC[S][t] + DdEff * rx[S][t];
        __builtin_amdgcn_wave_barrier();
        float sum = 0.f;
        #pragma unroll
        for (int k = 0; k < 16; ++k)
            sum += ps[w][t_r][k * 4 + cl_r];
        float zz = rz[S];
        float sz = zz / (1.f + __expf(-zz));
        float val = sum * sz;
        ushort_t hh = f2bf_rne(val);
        ushort_t ll = f2bf_rne(val - bf2f(hh));
        size_t om = (size_t)(base + c * 16 + t_r) * D_INNER + d_out;
        Yh[om] = hh; Yl[om] = ll;
        __builtin_amdgcn_wave_barrier();
    }
#undef LOADC
#undef PREPC
}

// ---------------------------------------------------------------------------
extern "C" void kernel_launch(void* const* d_in, const int* in_sizes, int n_in,
                              void* d_out, int out_size, void* d_ws, size_t ws_size,
                              hipStream_t stream)
{
    const float* x       = (const float*)d_in[0];
    const float* W_in    = (const float*)d_in[1];
    const float* W_conv  = (const float*)d_in[2];
    const float* b_conv  = (const float*)d_in[3];
    const float* W_xproj = (const float*)d_in[4];
    const float* W_dt    = (const float*)d_in[5];
    const float* b_dt    = (const float*)d_in[6];
    const float* A_log   = (const float*)d_in[7];
    const float* Dv      = (const float*)d_in[8];
    const float* W_out   = (const float*)d_in[9];
    float* out = (float*)d_out;

    // fp32 region
    float* xz  = (float*)d_ws;                               // 16.78M f
    float* dbc = xz + (size_t)M_TOT * 2 * D_INNER;           // 4096*128 f
    float* BCT = dbc + (size_t)M_TOT * DBC_STRIDE;           // 32*4096 f
    // bf16 region
    ushort_t* xh     = (ushort_t*)(BCT + (size_t)32 * M_TOT);
    ushort_t* xl     = xh + (size_t)M_TOT * D_MODEL;
    ushort_t* WinTh  = xl + (size_t)M_TOT * D_MODEL;          // [4096][1024]
    ushort_t* WinTl  = WinTh + (size_t)2 * D_INNER * D_MODEL;
    ushort_t* WoutTh = WinTl + (size_t)2 * D_INNER * D_MODEL; // [1024][2048]
    ushort_t* WoutTl = WoutTh + (size_t)D_MODEL * D_INNER;
    ushort_t* WxTh   = WoutTl + (size_t)D_MODEL * D_INNER;    // [128][2048]
    ushort_t* WxTl   = WxTh + (size_t)DBC_STRIDE * D_INNER;
    ushort_t* xinh   = WxTl + (size_t)DBC_STRIDE * D_INNER;   // [4096][2048]
    ushort_t* xinl   = xinh + (size_t)M_TOT * D_INNER;
    ushort_t* yh     = xinl + (size_t)M_TOT * D_INNER;        // [4096][2048]
    ushort_t* yl     = yh + (size_t)M_TOT * D_INNER;
    // aliases (stream-ordered reuse of dead regions):
    float* xT  = (float*)xh;     // [2048][4096] fp32 over xh|xl|WinTh|WinTl (dead after gemm#1)
    float* dtT = (float*)xinh;   // [2048][4096] fp32 over xinh|xinl (dead after xproj gemm)

    // precompute: casts + weight transposes
    cast_hl_k<<<(M_TOT * D_MODEL) / 1024, 256, 0, stream>>>(x, xh, xl);
    transpose_cast_k<<<dim3((2 * D_INNER) / 32, D_MODEL / 32), 256, 0, stream>>>(
        W_in, WinTh, WinTl, D_MODEL, 2 * D_INNER);
    transpose_cast_k<<<dim3(D_MODEL / 32, D_INNER / 32), 256, 0, stream>>>(
        W_out, WoutTh, WoutTl, D_INNER, D_MODEL);
    transpose_cast_pad_k<<<dim3(DBC_STRIDE / 32, D_INNER / 32), 256, 0, stream>>>(
        W_xproj, WxTh, WxTl, D_INNER, DT_RANK + 2 * D_STATE);

    // 1) xz = x @ W_in          (M=4096, N=4096, K=1024)
    gemm_bf16s<false><<<dim3(32, 32), 256, 0, stream>>>(
        xh, xl, WinTh, WinTl, xz, nullptr, M_TOT, 2 * D_INNER, D_MODEL);
    // 2) conv + silu -> xinh/xinl [m][d] + xT [d][m]   (overwrites xh/xl/WinT)
    conv_silu_k<<<dim3(D_INNER / 64, M_TOT / 64), 256, 0, stream>>>(
        xz, W_conv, b_conv, xinh, xinl, xT);
    // 3) dbc = x_in @ W_xproj   (N=128 padded) + BCT time-major B/C
    gemm_bf16s<true><<<dim3(1, 32), 256, 0, stream>>>(
        xinh, xinl, WxTh, WxTl, dbc, BCT, M_TOT, DBC_STRIDE, D_INNER);
    // 4) dt -> dtT [d][m]       (overwrites xinh/xinl)
    dtproj_k<<<dim3(D_INNER / 256, M_TOT / 16), 256, 0, stream>>>(dbc, W_dt, b_dt, dtT);
    // 5) scan + gate -> yh/yl bf16
    scan_k<<<NBATCH * (D_INNER / 16), 256, 0, stream>>>(
        dtT, xT, BCT, xz, A_log, Dv, yh, yl);
    // 6) out = y @ W_out        (M=4096, N=1024, K=2048)
    gemm_bf16s<false><<<dim3(8, 32), 256, 0, stream>>>(
        yh, yl, WoutTh, WoutTl, out, nullptr, M_TOT, D_MODEL, D_INNER);
}